// Round 2
// baseline (617.815 us; speedup 1.0000x reference)
//
#include <hip/hip_runtime.h>
#include <hip/hip_bf16.h>
#include <cstdint>
#include <cstddef>

typedef __bf16 bf16_t;
typedef __bf16 bf16x8 __attribute__((ext_vector_type(8)));
typedef float f32x4 __attribute__((ext_vector_type(4)));

#define NROWS 8192
#define DFEAT 1024
#define BK 32

typedef __attribute__((address_space(3))) unsigned int lds_uint;
typedef __attribute__((address_space(1))) const unsigned int glb_uint;

__device__ __forceinline__ float fast_tanh(float x) {
  // tanh via exp2-based expf; rcp intrinsic (1-ulp-ish) is fine at our tolerance
  float e = __expf(2.0f * x);
  return 1.0f - 2.0f * __builtin_amdgcn_rcpf(e + 1.0f);
}

__global__ __launch_bounds__(256) void split_kernel(const float* __restrict__ in,
                                                    bf16_t* __restrict__ hi,
                                                    bf16_t* __restrict__ lo, int n) {
  int i = blockIdx.x * 256 + threadIdx.x;
  if (i < n) {
    float v = in[i];
    bf16_t h = (bf16_t)v;
    hi[i] = h;
    lo[i] = (bf16_t)(v - (float)h);
  }
}

// Async-stage a 128x32 bf16 tile from row-major g (leading dim ld) into LDS
// laid out row-major [128][32] (contiguous, unpadded — required by the
// wave-uniform-base + lane*16 semantics of global_load_lds).
__device__ __forceinline__ void stage_async(const bf16_t* __restrict__ g, int ld,
                                            int row0, int k0, bf16_t* lds,
                                            int wave, int lane) {
#pragma unroll
  for (int t = 0; t < 2; ++t) {
    const int rb = (t * 4 + wave) * 16;  // 16 rows per wave-issue
    const bf16_t* gp = g + (size_t)(row0 + rb + (lane >> 2)) * ld + (k0 + (lane & 3) * 8);
    __builtin_amdgcn_global_load_lds((glb_uint*)gp, (lds_uint*)(lds + rb * BK), 16, 0, 0);
  }
}

// h = x @ W^T + b in split-bf16 (hh + hl + lh), output bf16
__global__ __launch_bounds__(256) void gemm1_kernel(const bf16_t* __restrict__ xh,
                                                    const bf16_t* __restrict__ xl,
                                                    const bf16_t* __restrict__ Wh,
                                                    const bf16_t* __restrict__ Wl,
                                                    const float* __restrict__ bias,
                                                    bf16_t* __restrict__ hout) {
  __shared__ bf16_t lAh[128 * BK], lAl[128 * BK], lBh[128 * BK], lBl[128 * BK];
  const int tid = threadIdx.x;
  const int wave = tid >> 6, lane = tid & 63;
  const int wm = wave >> 1, wn = wave & 1;
  const int l15 = lane & 15, quad = lane >> 4;
  const int m0 = blockIdx.y * 128, n0 = blockIdx.x * 128;
  f32x4 acc[4][4] = {};
  for (int k0 = 0; k0 < DFEAT; k0 += BK) {
    __syncthreads();
    stage_async(xh, DFEAT, m0, k0, lAh, wave, lane);
    stage_async(xl, DFEAT, m0, k0, lAl, wave, lane);
    stage_async(Wh, DFEAT, n0, k0, lBh, wave, lane);
    stage_async(Wl, DFEAT, n0, k0, lBl, wave, lane);
    __syncthreads();  // compiler drains vmcnt before s_barrier
    bf16x8 ah[4], al[4], bh[4], bl[4];
#pragma unroll
    for (int f = 0; f < 4; ++f) {
      int ar = wm * 64 + f * 16 + l15, br = wn * 64 + f * 16 + l15;
      ah[f] = *(const bf16x8*)(lAh + ar * BK + quad * 8);
      al[f] = *(const bf16x8*)(lAl + ar * BK + quad * 8);
      bh[f] = *(const bf16x8*)(lBh + br * BK + quad * 8);
      bl[f] = *(const bf16x8*)(lBl + br * BK + quad * 8);
    }
#pragma unroll
    for (int i = 0; i < 4; ++i)
#pragma unroll
      for (int j = 0; j < 4; ++j) {
        acc[i][j] = __builtin_amdgcn_mfma_f32_16x16x32_bf16(ah[i], bh[j], acc[i][j], 0, 0, 0);
        acc[i][j] = __builtin_amdgcn_mfma_f32_16x16x32_bf16(ah[i], bl[j], acc[i][j], 0, 0, 0);
        acc[i][j] = __builtin_amdgcn_mfma_f32_16x16x32_bf16(al[i], bh[j], acc[i][j], 0, 0, 0);
      }
  }
#pragma unroll
  for (int i = 0; i < 4; ++i) {
    int rbase = m0 + wm * 64 + i * 16 + quad * 4;
#pragma unroll
    for (int j = 0; j < 4; ++j) {
      int col = n0 + wn * 64 + j * 16 + l15;
      float bv = bias[col];
#pragma unroll
      for (int r = 0; r < 4; ++r)
        hout[(size_t)(rbase + r) * DFEAT + col] = (bf16_t)(acc[i][j][r] + bv);
    }
  }
}

__global__ __launch_bounds__(256) void transpose_kernel(const bf16_t* __restrict__ in,
                                                        bf16_t* __restrict__ outT) {
  __shared__ bf16_t tile[64][65];
  int bm = blockIdx.y * 64, bn = blockIdx.x * 64;
  int tid = threadIdx.x;
  int x = tid & 63, y0 = tid >> 6;
#pragma unroll
  for (int i = 0; i < 16; ++i) {
    int r = y0 * 16 + i;
    tile[r][x] = in[(size_t)(bm + r) * DFEAT + bn + x];
  }
  __syncthreads();
#pragma unroll
  for (int i = 0; i < 16; ++i) {
    int r = y0 * 16 + i;
    outT[(size_t)(bn + r) * NROWS + bm + x] = tile[x][r];
  }
}

// P = exp(tanh(h @ h^T)) (bf16) + fused row-sum accumulation into lsum (atomics)
__global__ __launch_bounds__(256) void scores_kernel(const bf16_t* __restrict__ h,
                                                     bf16_t* __restrict__ P,
                                                     float* __restrict__ lsum) {
  __shared__ bf16_t lA[128 * BK], lB[128 * BK];
  const int tid = threadIdx.x;
  const int wave = tid >> 6, lane = tid & 63;
  const int wm = wave >> 1, wn = wave & 1;
  const int l15 = lane & 15, quad = lane >> 4;
  const int m0 = blockIdx.y * 128, n0 = blockIdx.x * 128;
  f32x4 acc[4][4] = {};
  for (int k0 = 0; k0 < DFEAT; k0 += BK) {
    __syncthreads();
    stage_async(h, DFEAT, m0, k0, lA, wave, lane);
    stage_async(h, DFEAT, n0, k0, lB, wave, lane);
    __syncthreads();
    bf16x8 a[4], b[4];
#pragma unroll
    for (int f = 0; f < 4; ++f) {
      a[f] = *(const bf16x8*)(lA + (wm * 64 + f * 16 + l15) * BK + quad * 8);
      b[f] = *(const bf16x8*)(lB + (wn * 64 + f * 16 + l15) * BK + quad * 8);
    }
#pragma unroll
    for (int i = 0; i < 4; ++i)
#pragma unroll
      for (int j = 0; j < 4; ++j)
        acc[i][j] = __builtin_amdgcn_mfma_f32_16x16x32_bf16(a[i], b[j], acc[i][j], 0, 0, 0);
  }
  // epilogue: p = exp(tanh(s)); store P; fold partial row-sums
  float rs[4][4];  // [i][r] partial sums over this lane's 4 cols
#pragma unroll
  for (int i = 0; i < 4; ++i) {
    int rbase = m0 + wm * 64 + i * 16 + quad * 4;
#pragma unroll
    for (int r = 0; r < 4; ++r) rs[i][r] = 0.f;
#pragma unroll
    for (int j = 0; j < 4; ++j) {
      int col = n0 + wn * 64 + j * 16 + l15;
#pragma unroll
      for (int r = 0; r < 4; ++r) {
        float p = __expf(fast_tanh(acc[i][j][r]));
        rs[i][r] += p;
        P[(size_t)(rbase + r) * NROWS + col] = (bf16_t)p;
      }
    }
  }
  // reduce rs across the 16 lanes sharing a quad (same rows)
#pragma unroll
  for (int off = 1; off < 16; off <<= 1)
#pragma unroll
    for (int i = 0; i < 4; ++i)
#pragma unroll
      for (int r = 0; r < 4; ++r) rs[i][r] += __shfl_xor(rs[i][r], off, 64);
  if (l15 == 0) {
#pragma unroll
    for (int i = 0; i < 4; ++i) {
      int rbase = m0 + wm * 64 + i * 16 + quad * 4;
#pragma unroll
      for (int r = 0; r < 4; ++r) atomicAdd(&lsum[rbase + r], rs[i][r]);
    }
  }
}

// out = tanh((P @ h) / l)  with hT as row-major B operand
__global__ __launch_bounds__(256) void pv_kernel(const bf16_t* __restrict__ P,
                                                 const bf16_t* __restrict__ hT,
                                                 const float* __restrict__ lsum,
                                                 float* __restrict__ out) {
  __shared__ bf16_t lA[128 * BK], lB[128 * BK];
  const int tid = threadIdx.x;
  const int wave = tid >> 6, lane = tid & 63;
  const int wm = wave >> 1, wn = wave & 1;
  const int l15 = lane & 15, quad = lane >> 4;
  const int m0 = blockIdx.y * 128, n0 = blockIdx.x * 128;
  f32x4 acc[4][4] = {};
  for (int k0 = 0; k0 < NROWS; k0 += BK) {
    __syncthreads();
    stage_async(P, NROWS, m0, k0, lA, wave, lane);
    stage_async(hT, NROWS, n0, k0, lB, wave, lane);
    __syncthreads();
    bf16x8 a[4], b[4];
#pragma unroll
    for (int f = 0; f < 4; ++f) {
      a[f] = *(const bf16x8*)(lA + (wm * 64 + f * 16 + l15) * BK + quad * 8);
      b[f] = *(const bf16x8*)(lB + (wn * 64 + f * 16 + l15) * BK + quad * 8);
    }
#pragma unroll
    for (int i = 0; i < 4; ++i)
#pragma unroll
      for (int j = 0; j < 4; ++j)
        acc[i][j] = __builtin_amdgcn_mfma_f32_16x16x32_bf16(a[i], b[j], acc[i][j], 0, 0, 0);
  }
#pragma unroll
  for (int i = 0; i < 4; ++i) {
    int rbase = m0 + wm * 64 + i * 16 + quad * 4;
#pragma unroll
    for (int r = 0; r < 4; ++r) {
      float rl = __builtin_amdgcn_rcpf(lsum[rbase + r]);
#pragma unroll
      for (int j = 0; j < 4; ++j) {
        int col = n0 + wn * 64 + j * 16 + l15;
        out[(size_t)(rbase + r) * DFEAT + col] = fast_tanh(acc[i][j][r] * rl);
      }
    }
  }
}

extern "C" void kernel_launch(void* const* d_in, const int* in_sizes, int n_in,
                              void* d_out, int out_size, void* d_ws, size_t ws_size,
                              hipStream_t stream) {
  const float* x = (const float*)d_in[0];
  const float* W = (const float*)d_in[1];
  const float* bias = (const float*)d_in[2];
  float* out = (float*)d_out;

  bf16_t* xh = (bf16_t*)d_ws;
  bf16_t* xl = xh + (size_t)NROWS * DFEAT;
  bf16_t* Wh = xl + (size_t)NROWS * DFEAT;
  bf16_t* Wl = Wh + (size_t)DFEAT * DFEAT;
  bf16_t* h  = Wl + (size_t)DFEAT * DFEAT;
  bf16_t* hT = h + (size_t)NROWS * DFEAT;
  float* lsum = (float*)(hT + (size_t)NROWS * DFEAT);
  bf16_t* P = (bf16_t*)(lsum + NROWS);

  split_kernel<<<(NROWS * DFEAT) / 256, 256, 0, stream>>>(x, xh, xl, NROWS * DFEAT);
  split_kernel<<<(DFEAT * DFEAT) / 256, 256, 0, stream>>>(W, Wh, Wl, DFEAT * DFEAT);
  gemm1_kernel<<<dim3(DFEAT / 128, NROWS / 128), 256, 0, stream>>>(xh, xl, Wh, Wl, bias, h);
  transpose_kernel<<<dim3(DFEAT / 64, NROWS / 64), 256, 0, stream>>>(h, hT);
  hipMemsetAsync(lsum, 0, NROWS * sizeof(float), stream);
  scores_kernel<<<dim3(NROWS / 128, NROWS / 128), 256, 0, stream>>>(h, P, lsum);
  pv_kernel<<<dim3(DFEAT / 128, NROWS / 128), 256, 0, stream>>>(P, hT, lsum, out);
}

// Round 3
// 532.076 us; speedup vs baseline: 1.1611x; 1.1611x over previous
//
#include <hip/hip_runtime.h>
#include <hip/hip_bf16.h>
#include <cstdint>
#include <cstddef>

typedef __bf16 bf16_t;
typedef __bf16 bf16x8 __attribute__((ext_vector_type(8)));
typedef float f32x4 __attribute__((ext_vector_type(4)));

#define NROWS 8192
#define DFEAT 1024
#define BK 32
#define NBLK 64  // NROWS/128

typedef __attribute__((address_space(3))) unsigned int lds_uint;
typedef __attribute__((address_space(1))) const unsigned int glb_uint;

__device__ __forceinline__ float fast_tanh(float x) {
  float e = __expf(2.0f * x);
  return 1.0f - 2.0f * __builtin_amdgcn_rcpf(e + 1.0f);
}

__global__ __launch_bounds__(256) void split_kernel(const float* __restrict__ in,
                                                    bf16_t* __restrict__ hi,
                                                    bf16_t* __restrict__ lo, int n) {
  int i = blockIdx.x * 256 + threadIdx.x;
  if (i < n) {
    float v = in[i];
    bf16_t h = (bf16_t)v;
    hi[i] = h;
    lo[i] = (bf16_t)(v - (float)h);
  }
}

// Async-stage a 128x32 bf16 tile into contiguous LDS [128][32] via global_load_lds w16.
__device__ __forceinline__ void stage_async(const bf16_t* __restrict__ g, int ld,
                                            int row0, int k0, bf16_t* lds,
                                            int wave, int lane) {
#pragma unroll
  for (int t = 0; t < 2; ++t) {
    const int rb = (t * 4 + wave) * 16;
    const bf16_t* gp = g + (size_t)(row0 + rb + (lane >> 2)) * ld + (k0 + (lane & 3) * 8);
    __builtin_amdgcn_global_load_lds((glb_uint*)gp, (lds_uint*)(lds + rb * BK), 16, 0, 0);
  }
}

// h = x @ W^T + b in split-bf16 (hh + hl + lh), output bf16
__global__ __launch_bounds__(256) void gemm1_kernel(const bf16_t* __restrict__ xh,
                                                    const bf16_t* __restrict__ xl,
                                                    const bf16_t* __restrict__ Wh,
                                                    const bf16_t* __restrict__ Wl,
                                                    const float* __restrict__ bias,
                                                    bf16_t* __restrict__ hout) {
  __shared__ bf16_t lAh[128 * BK], lAl[128 * BK], lBh[128 * BK], lBl[128 * BK];
  const int tid = threadIdx.x;
  const int wave = tid >> 6, lane = tid & 63;
  const int wm = wave >> 1, wn = wave & 1;
  const int l15 = lane & 15, quad = lane >> 4;
  const int m0 = blockIdx.y * 128, n0 = blockIdx.x * 128;
  f32x4 acc[4][4] = {};
  for (int k0 = 0; k0 < DFEAT; k0 += BK) {
    __syncthreads();
    stage_async(xh, DFEAT, m0, k0, lAh, wave, lane);
    stage_async(xl, DFEAT, m0, k0, lAl, wave, lane);
    stage_async(Wh, DFEAT, n0, k0, lBh, wave, lane);
    stage_async(Wl, DFEAT, n0, k0, lBl, wave, lane);
    __syncthreads();
    bf16x8 ah[4], al[4], bh[4], bl[4];
#pragma unroll
    for (int f = 0; f < 4; ++f) {
      int ar = wm * 64 + f * 16 + l15, br = wn * 64 + f * 16 + l15;
      ah[f] = *(const bf16x8*)(lAh + ar * BK + quad * 8);
      al[f] = *(const bf16x8*)(lAl + ar * BK + quad * 8);
      bh[f] = *(const bf16x8*)(lBh + br * BK + quad * 8);
      bl[f] = *(const bf16x8*)(lBl + br * BK + quad * 8);
    }
#pragma unroll
    for (int i = 0; i < 4; ++i)
#pragma unroll
      for (int j = 0; j < 4; ++j) {
        acc[i][j] = __builtin_amdgcn_mfma_f32_16x16x32_bf16(ah[i], bh[j], acc[i][j], 0, 0, 0);
        acc[i][j] = __builtin_amdgcn_mfma_f32_16x16x32_bf16(ah[i], bl[j], acc[i][j], 0, 0, 0);
        acc[i][j] = __builtin_amdgcn_mfma_f32_16x16x32_bf16(al[i], bh[j], acc[i][j], 0, 0, 0);
      }
  }
#pragma unroll
  for (int i = 0; i < 4; ++i) {
    int rbase = m0 + wm * 64 + i * 16 + quad * 4;
#pragma unroll
    for (int j = 0; j < 4; ++j) {
      int col = n0 + wn * 64 + j * 16 + l15;
      float bv = bias[col];
#pragma unroll
      for (int r = 0; r < 4; ++r)
        hout[(size_t)(rbase + r) * DFEAT + col] = (bf16_t)(acc[i][j][r] + bv);
    }
  }
}

__global__ __launch_bounds__(256) void transpose_kernel(const bf16_t* __restrict__ in,
                                                        bf16_t* __restrict__ outT) {
  __shared__ bf16_t tile[64][65];
  int bm = blockIdx.y * 64, bn = blockIdx.x * 64;
  int tid = threadIdx.x;
  int x = tid & 63, y0 = tid >> 6;
#pragma unroll
  for (int i = 0; i < 16; ++i) {
    int r = y0 * 16 + i;
    tile[r][x] = in[(size_t)(bm + r) * DFEAT + bn + x];
  }
  __syncthreads();
#pragma unroll
  for (int i = 0; i < 16; ++i) {
    int r = y0 * 16 + i;
    outT[(size_t)(bn + r) * NROWS + bm + x] = tile[x][r];
  }
}

// Symmetric scores: compute only upper-triangular 128x128 tiles of
// P = exp(tanh(h h^T)); write tile + LDS-transposed mirror; fold row-sums and
// col-sums into lsum. S is exactly symmetric (MFMA dot products commute).
__global__ __launch_bounds__(256) void scores_sym_kernel(const bf16_t* __restrict__ h,
                                                         bf16_t* __restrict__ P,
                                                         float* __restrict__ lsum) {
  // smem overlay: staging (16 KB) during K-loop, mirror tile [128][136] after.
  __shared__ __align__(16) char smem[128 * 136 * 2];
  bf16_t* lA = (bf16_t*)smem;
  bf16_t* lB = (bf16_t*)(smem + 128 * BK * 2);
  bf16_t (*mir)[136] = (bf16_t(*)[136])smem;

  // triangular decode: blockIdx.x -> (bm, bn), bm <= bn
  int t = blockIdx.x, bm = 0;
  while (t >= NBLK - bm) { t -= NBLK - bm; ++bm; }
  const int bn = bm + t;
  const bool offdiag = (bm != bn);
  const int m0 = bm * 128, n0 = bn * 128;

  const int tid = threadIdx.x;
  const int wave = tid >> 6, lane = tid & 63;
  const int wm = wave >> 1, wn = wave & 1;
  const int l15 = lane & 15, quad = lane >> 4;

  f32x4 acc[4][4] = {};
  for (int k0 = 0; k0 < DFEAT; k0 += BK) {
    __syncthreads();
    stage_async(h, DFEAT, m0, k0, lA, wave, lane);
    stage_async(h, DFEAT, n0, k0, lB, wave, lane);
    __syncthreads();
    bf16x8 a[4], b[4];
#pragma unroll
    for (int f = 0; f < 4; ++f) {
      a[f] = *(const bf16x8*)(lA + (wm * 64 + f * 16 + l15) * BK + quad * 8);
      b[f] = *(const bf16x8*)(lB + (wn * 64 + f * 16 + l15) * BK + quad * 8);
    }
#pragma unroll
    for (int i = 0; i < 4; ++i)
#pragma unroll
      for (int j = 0; j < 4; ++j)
        acc[i][j] = __builtin_amdgcn_mfma_f32_16x16x32_bf16(a[i], b[j], acc[i][j], 0, 0, 0);
  }
  __syncthreads();  // staging reads done; smem now free for mirror tile

  float rs[4][4];   // row partials: [i][r]
  float cs[4];      // col partials: [j] (this lane's col = wn*64+j*16+l15)
#pragma unroll
  for (int i = 0; i < 4; ++i)
#pragma unroll
    for (int r = 0; r < 4; ++r) rs[i][r] = 0.f;
#pragma unroll
  for (int j = 0; j < 4; ++j) cs[j] = 0.f;

#pragma unroll
  for (int i = 0; i < 4; ++i) {
    const int rl_loc = wm * 64 + i * 16 + quad * 4;  // local row of first elem
    const int rbase = m0 + rl_loc;
#pragma unroll
    for (int j = 0; j < 4; ++j) {
      const int cl_loc = wn * 64 + j * 16 + l15;     // local col
      const int col = n0 + cl_loc;
      bf16_t pbv[4];
#pragma unroll
      for (int r = 0; r < 4; ++r) {
        float p = __expf(fast_tanh(acc[i][j][r]));
        pbv[r] = (bf16_t)p;
        rs[i][r] += p;
        cs[j] += p;
        P[(size_t)(rbase + r) * NROWS + col] = pbv[r];
      }
      if (offdiag) __builtin_memcpy(&mir[cl_loc][rl_loc], pbv, 8);  // ds_write_b64
    }
  }

  // row-sum reduce across the 16 l15 lanes (same rows)
#pragma unroll
  for (int off = 1; off < 16; off <<= 1)
#pragma unroll
    for (int i = 0; i < 4; ++i)
#pragma unroll
      for (int r = 0; r < 4; ++r) rs[i][r] += __shfl_xor(rs[i][r], off, 64);
  if (l15 == 0) {
#pragma unroll
    for (int i = 0; i < 4; ++i) {
      int rbase = m0 + wm * 64 + i * 16 + quad * 4;
#pragma unroll
      for (int r = 0; r < 4; ++r) atomicAdd(&lsum[rbase + r], rs[i][r]);
    }
  }

  if (offdiag) {
    // col-sum reduce across the 4 quads (same col)
#pragma unroll
    for (int off = 16; off < 64; off <<= 1)
#pragma unroll
      for (int j = 0; j < 4; ++j) cs[j] += __shfl_xor(cs[j], off, 64);
    if (quad == 0) {
#pragma unroll
      for (int j = 0; j < 4; ++j)
        atomicAdd(&lsum[n0 + wn * 64 + j * 16 + l15], cs[j]);
    }
    // mirror tile write-out: P[n0+c][m0 .. m0+127] = mir[c][0..127]
    __syncthreads();
#pragma unroll
    for (int it = 0; it < 8; ++it) {
      int q = tid + it * 256;          // 0..2047
      int c = q >> 4, r0 = (q & 15) * 8;
      bf16x8 v = *(const bf16x8*)(&mir[c][r0]);
      *(bf16x8*)(P + (size_t)(n0 + c) * NROWS + m0 + r0) = v;
    }
  }
}

// pv partial: part = P[:, ks] @ hT[:, ks]^T  (raw fp32 sums, split-K over z)
__global__ __launch_bounds__(256) void pv_kernel(const bf16_t* __restrict__ P,
                                                 const bf16_t* __restrict__ hT,
                                                 float* __restrict__ part0,
                                                 float* __restrict__ part1) {
  __shared__ bf16_t lA[128 * BK], lB[128 * BK];
  const int tid = threadIdx.x;
  const int wave = tid >> 6, lane = tid & 63;
  const int wm = wave >> 1, wn = wave & 1;
  const int l15 = lane & 15, quad = lane >> 4;
  const int m0 = blockIdx.y * 128, n0 = blockIdx.x * 128;
  const int s = blockIdx.z;
  float* __restrict__ part = s ? part1 : part0;
  f32x4 acc[4][4] = {};
  const int kbeg = s * (NROWS / 2), kend = kbeg + NROWS / 2;
  for (int k0 = kbeg; k0 < kend; k0 += BK) {
    __syncthreads();
    stage_async(P, NROWS, m0, k0, lA, wave, lane);
    stage_async(hT, NROWS, n0, k0, lB, wave, lane);
    __syncthreads();
    bf16x8 a[4], b[4];
#pragma unroll
    for (int f = 0; f < 4; ++f) {
      a[f] = *(const bf16x8*)(lA + (wm * 64 + f * 16 + l15) * BK + quad * 8);
      b[f] = *(const bf16x8*)(lB + (wn * 64 + f * 16 + l15) * BK + quad * 8);
    }
#pragma unroll
    for (int i = 0; i < 4; ++i)
#pragma unroll
      for (int j = 0; j < 4; ++j)
        acc[i][j] = __builtin_amdgcn_mfma_f32_16x16x32_bf16(a[i], b[j], acc[i][j], 0, 0, 0);
  }
#pragma unroll
  for (int i = 0; i < 4; ++i) {
    int rbase = m0 + wm * 64 + i * 16 + quad * 4;
#pragma unroll
    for (int r = 0; r < 4; ++r)
#pragma unroll
      for (int j = 0; j < 4; ++j) {
        int col = n0 + wn * 64 + j * 16 + l15;
        part[(size_t)(rbase + r) * DFEAT + col] = acc[i][j][r];
      }
  }
}

// out = tanh((part0 + part1) / l), vectorized x4
__global__ __launch_bounds__(256) void pv_epilogue(float* __restrict__ out,
                                                   const float* __restrict__ part1,
                                                   const float* __restrict__ lsum) {
  int i = (blockIdx.x * 256 + threadIdx.x) * 4;
  float4 a = *(const float4*)(out + i);
  float4 b = *(const float4*)(part1 + i);
  float rl = __builtin_amdgcn_rcpf(lsum[i >> 10]);
  float4 o;
  o.x = fast_tanh((a.x + b.x) * rl);
  o.y = fast_tanh((a.y + b.y) * rl);
  o.z = fast_tanh((a.z + b.z) * rl);
  o.w = fast_tanh((a.w + b.w) * rl);
  *(float4*)(out + i) = o;
}

extern "C" void kernel_launch(void* const* d_in, const int* in_sizes, int n_in,
                              void* d_out, int out_size, void* d_ws, size_t ws_size,
                              hipStream_t stream) {
  const float* x = (const float*)d_in[0];
  const float* W = (const float*)d_in[1];
  const float* bias = (const float*)d_in[2];
  float* out = (float*)d_out;

  bf16_t* xh = (bf16_t*)d_ws;
  bf16_t* xl = xh + (size_t)NROWS * DFEAT;
  bf16_t* Wh = xl + (size_t)NROWS * DFEAT;
  bf16_t* Wl = Wh + (size_t)DFEAT * DFEAT;
  bf16_t* h  = Wl + (size_t)DFEAT * DFEAT;
  bf16_t* hT = h + (size_t)NROWS * DFEAT;
  float* lsum = (float*)(hT + (size_t)NROWS * DFEAT);
  bf16_t* P = (bf16_t*)(lsum + NROWS);
  // pv split-K partial 1 overlays the (dead after gemm1) xh/xl region:
  // 8192*1024 fp32 = 33,554,432 B == sizeof(xh)+sizeof(xl) exactly.
  float* part1 = (float*)d_ws;

  split_kernel<<<(NROWS * DFEAT) / 256, 256, 0, stream>>>(x, xh, xl, NROWS * DFEAT);
  split_kernel<<<(DFEAT * DFEAT) / 256, 256, 0, stream>>>(W, Wh, Wl, DFEAT * DFEAT);
  gemm1_kernel<<<dim3(DFEAT / 128, NROWS / 128), 256, 0, stream>>>(xh, xl, Wh, Wl, bias, h);
  transpose_kernel<<<dim3(DFEAT / 64, NROWS / 64), 256, 0, stream>>>(h, hT);
  hipMemsetAsync(lsum, 0, NROWS * sizeof(float), stream);
  scores_sym_kernel<<<NBLK * (NBLK + 1) / 2, 256, 0, stream>>>(h, P, lsum);
  pv_kernel<<<dim3(DFEAT / 128, NROWS / 128, 2), 256, 0, stream>>>(P, hT, out, part1);
  pv_epilogue<<<(NROWS * DFEAT) / 1024, 256, 0, stream>>>(out, part1, lsum);
}

// Round 4
// 531.694 us; speedup vs baseline: 1.1620x; 1.0007x over previous
//
#include <hip/hip_runtime.h>
#include <hip/hip_bf16.h>
#include <cstdint>
#include <cstddef>

typedef __bf16 bf16_t;
typedef __bf16 bf16x8 __attribute__((ext_vector_type(8)));
typedef float f32x4 __attribute__((ext_vector_type(4)));

#define NROWS 8192
#define DFEAT 1024
#define BK 32
#define NBLK 64  // NROWS/128
#define TILE_B (128 * BK)  // bf16 elems per staged tile (8 KB)

typedef __attribute__((address_space(3))) unsigned int lds_uint;
typedef __attribute__((address_space(1))) const unsigned int glb_uint;

__device__ __forceinline__ float fast_tanh(float x) {
  float e = __expf(2.0f * x);
  return 1.0f - 2.0f * __builtin_amdgcn_rcpf(e + 1.0f);
}

__global__ __launch_bounds__(256) void split_kernel(const float* __restrict__ in,
                                                    bf16_t* __restrict__ hi,
                                                    bf16_t* __restrict__ lo, int n) {
  int i = blockIdx.x * 256 + threadIdx.x;
  if (i < n) {
    float v = in[i];
    bf16_t h = (bf16_t)v;
    hi[i] = h;
    lo[i] = (bf16_t)(v - (float)h);
  }
}

// Async-stage a 128x32 bf16 tile into contiguous LDS [128][32] via global_load_lds w16.
__device__ __forceinline__ void stage_async(const bf16_t* __restrict__ g, int ld,
                                            int row0, int k0, bf16_t* lds,
                                            int wave, int lane) {
#pragma unroll
  for (int t = 0; t < 2; ++t) {
    const int rb = (t * 4 + wave) * 16;
    const bf16_t* gp = g + (size_t)(row0 + rb + (lane >> 2)) * ld + (k0 + (lane & 3) * 8);
    __builtin_amdgcn_global_load_lds((glb_uint*)gp, (lds_uint*)(lds + rb * BK), 16, 0, 0);
  }
}

// h = x @ W^T + b in split-bf16 (hh + hl + lh), output bf16
__global__ __launch_bounds__(256) void gemm1_kernel(const bf16_t* __restrict__ xh,
                                                    const bf16_t* __restrict__ xl,
                                                    const bf16_t* __restrict__ Wh,
                                                    const bf16_t* __restrict__ Wl,
                                                    const float* __restrict__ bias,
                                                    bf16_t* __restrict__ hout) {
  __shared__ bf16_t lAh[TILE_B], lAl[TILE_B], lBh[TILE_B], lBl[TILE_B];
  const int tid = threadIdx.x;
  const int wave = tid >> 6, lane = tid & 63;
  const int wm = wave >> 1, wn = wave & 1;
  const int l15 = lane & 15, quad = lane >> 4;
  const int m0 = blockIdx.y * 128, n0 = blockIdx.x * 128;
  f32x4 acc[4][4] = {};
  for (int k0 = 0; k0 < DFEAT; k0 += BK) {
    __syncthreads();
    stage_async(xh, DFEAT, m0, k0, lAh, wave, lane);
    stage_async(xl, DFEAT, m0, k0, lAl, wave, lane);
    stage_async(Wh, DFEAT, n0, k0, lBh, wave, lane);
    stage_async(Wl, DFEAT, n0, k0, lBl, wave, lane);
    __syncthreads();
    bf16x8 ah[4], al[4], bh[4], bl[4];
#pragma unroll
    for (int f = 0; f < 4; ++f) {
      int ar = wm * 64 + f * 16 + l15, br = wn * 64 + f * 16 + l15;
      ah[f] = *(const bf16x8*)(lAh + ar * BK + quad * 8);
      al[f] = *(const bf16x8*)(lAl + ar * BK + quad * 8);
      bh[f] = *(const bf16x8*)(lBh + br * BK + quad * 8);
      bl[f] = *(const bf16x8*)(lBl + br * BK + quad * 8);
    }
#pragma unroll
    for (int i = 0; i < 4; ++i)
#pragma unroll
      for (int j = 0; j < 4; ++j) {
        acc[i][j] = __builtin_amdgcn_mfma_f32_16x16x32_bf16(ah[i], bh[j], acc[i][j], 0, 0, 0);
        acc[i][j] = __builtin_amdgcn_mfma_f32_16x16x32_bf16(ah[i], bl[j], acc[i][j], 0, 0, 0);
        acc[i][j] = __builtin_amdgcn_mfma_f32_16x16x32_bf16(al[i], bh[j], acc[i][j], 0, 0, 0);
      }
  }
#pragma unroll
  for (int i = 0; i < 4; ++i) {
    int rbase = m0 + wm * 64 + i * 16 + quad * 4;
#pragma unroll
    for (int j = 0; j < 4; ++j) {
      int col = n0 + wn * 64 + j * 16 + l15;
      float bv = bias[col];
#pragma unroll
      for (int r = 0; r < 4; ++r)
        hout[(size_t)(rbase + r) * DFEAT + col] = (bf16_t)(acc[i][j][r] + bv);
    }
  }
}

__global__ __launch_bounds__(256) void transpose_kernel(const bf16_t* __restrict__ in,
                                                        bf16_t* __restrict__ outT) {
  __shared__ bf16_t tile[64][65];
  int bm = blockIdx.y * 64, bn = blockIdx.x * 64;
  int tid = threadIdx.x;
  int x = tid & 63, y0 = tid >> 6;
#pragma unroll
  for (int i = 0; i < 16; ++i) {
    int r = y0 * 16 + i;
    tile[r][x] = in[(size_t)(bm + r) * DFEAT + bn + x];
  }
  __syncthreads();
#pragma unroll
  for (int i = 0; i < 16; ++i) {
    int r = y0 * 16 + i;
    outT[(size_t)(bn + r) * NROWS + bm + x] = tile[x][r];
  }
}

// Symmetric scores, double-buffered staging: upper-triangular 128x128 tiles of
// P = exp(tanh(h h^T)); write tile + LDS-transposed mirror; fold row+col sums.
__global__ __launch_bounds__(256) void scores_sym_kernel(const bf16_t* __restrict__ h,
                                                         bf16_t* __restrict__ P,
                                                         float* __restrict__ lsum) {
  // smem: K-loop uses 2 phases x (lA 8KB + lB 8KB) = 32 KB; mirror tile
  // [128][136] bf16 = 34816 B overlays the whole region after the loop.
  __shared__ __align__(16) char smem[128 * 136 * 2];
  bf16_t (*mir)[136] = (bf16_t(*)[136])smem;

  int t = blockIdx.x, bm = 0;
  while (t >= NBLK - bm) { t -= NBLK - bm; ++bm; }
  const int bn = bm + t;
  const bool offdiag = (bm != bn);
  const int m0 = bm * 128, n0 = bn * 128;

  const int tid = threadIdx.x;
  const int wave = tid >> 6, lane = tid & 63;
  const int wm = wave >> 1, wn = wave & 1;
  const int l15 = lane & 15, quad = lane >> 4;

  f32x4 acc[4][4] = {};
  const int NIT = DFEAT / BK;
  stage_async(h, DFEAT, m0, 0, (bf16_t*)smem, wave, lane);
  stage_async(h, DFEAT, n0, 0, (bf16_t*)smem + TILE_B, wave, lane);
  __syncthreads();
  for (int it = 0; it < NIT; ++it) {
    bf16_t* lA = (bf16_t*)smem + (it & 1) * 2 * TILE_B;
    bf16_t* lB = lA + TILE_B;
    if (it + 1 < NIT) {
      bf16_t* nA = (bf16_t*)smem + ((it + 1) & 1) * 2 * TILE_B;
      stage_async(h, DFEAT, m0, (it + 1) * BK, nA, wave, lane);
      stage_async(h, DFEAT, n0, (it + 1) * BK, nA + TILE_B, wave, lane);
    }
    bf16x8 a[4], b[4];
#pragma unroll
    for (int f = 0; f < 4; ++f) {
      a[f] = *(const bf16x8*)(lA + (wm * 64 + f * 16 + l15) * BK + quad * 8);
      b[f] = *(const bf16x8*)(lB + (wn * 64 + f * 16 + l15) * BK + quad * 8);
    }
#pragma unroll
    for (int i = 0; i < 4; ++i)
#pragma unroll
      for (int j = 0; j < 4; ++j)
        acc[i][j] = __builtin_amdgcn_mfma_f32_16x16x32_bf16(a[i], b[j], acc[i][j], 0, 0, 0);
    __syncthreads();  // drains next-tile DMA (overlapped with compute above)
  }

  float rs[4][4];
  float cs[4];
#pragma unroll
  for (int i = 0; i < 4; ++i)
#pragma unroll
    for (int r = 0; r < 4; ++r) rs[i][r] = 0.f;
#pragma unroll
  for (int j = 0; j < 4; ++j) cs[j] = 0.f;

#pragma unroll
  for (int i = 0; i < 4; ++i) {
    const int rl_loc = wm * 64 + i * 16 + quad * 4;
    const int rbase = m0 + rl_loc;
#pragma unroll
    for (int j = 0; j < 4; ++j) {
      const int cl_loc = wn * 64 + j * 16 + l15;
      const int col = n0 + cl_loc;
      bf16_t pbv[4];
#pragma unroll
      for (int r = 0; r < 4; ++r) {
        float p = __expf(fast_tanh(acc[i][j][r]));
        pbv[r] = (bf16_t)p;
        rs[i][r] += p;
        cs[j] += p;
        P[(size_t)(rbase + r) * NROWS + col] = pbv[r];
      }
      if (offdiag) __builtin_memcpy(&mir[cl_loc][rl_loc], pbv, 8);
    }
  }

#pragma unroll
  for (int off = 1; off < 16; off <<= 1)
#pragma unroll
    for (int i = 0; i < 4; ++i)
#pragma unroll
      for (int r = 0; r < 4; ++r) rs[i][r] += __shfl_xor(rs[i][r], off, 64);
  if (l15 == 0) {
#pragma unroll
    for (int i = 0; i < 4; ++i) {
      int rbase = m0 + wm * 64 + i * 16 + quad * 4;
#pragma unroll
      for (int r = 0; r < 4; ++r) atomicAdd(&lsum[rbase + r], rs[i][r]);
    }
  }

  if (offdiag) {
#pragma unroll
    for (int off = 16; off < 64; off <<= 1)
#pragma unroll
      for (int j = 0; j < 4; ++j) cs[j] += __shfl_xor(cs[j], off, 64);
    if (quad == 0) {
#pragma unroll
      for (int j = 0; j < 4; ++j)
        atomicAdd(&lsum[n0 + wn * 64 + j * 16 + l15], cs[j]);
    }
    __syncthreads();
#pragma unroll
    for (int it = 0; it < 8; ++it) {
      int q = tid + it * 256;
      int c = q >> 4, r0 = (q & 15) * 8;
      bf16x8 v = *(const bf16x8*)(&mir[c][r0]);
      *(bf16x8*)(P + (size_t)(n0 + c) * NROWS + m0 + r0) = v;
    }
  }
}

// out = tanh((P @ h) / l), hT row-major B operand; double-buffered staging.
__global__ __launch_bounds__(256) void pv_kernel(const bf16_t* __restrict__ P,
                                                 const bf16_t* __restrict__ hT,
                                                 const float* __restrict__ lsum,
                                                 float* __restrict__ out) {
  __shared__ __align__(16) bf16_t smem[4 * TILE_B];  // 2 phases x (lA+lB) = 32 KB
  const int tid = threadIdx.x;
  const int wave = tid >> 6, lane = tid & 63;
  const int wm = wave >> 1, wn = wave & 1;
  const int l15 = lane & 15, quad = lane >> 4;
  const int m0 = blockIdx.y * 128, n0 = blockIdx.x * 128;
  f32x4 acc[4][4] = {};
  const int NIT = NROWS / BK;
  stage_async(P, NROWS, m0, 0, smem, wave, lane);
  stage_async(hT, NROWS, n0, 0, smem + TILE_B, wave, lane);
  __syncthreads();
  for (int it = 0; it < NIT; ++it) {
    bf16_t* lA = smem + (it & 1) * 2 * TILE_B;
    bf16_t* lB = lA + TILE_B;
    if (it + 1 < NIT) {
      bf16_t* nA = smem + ((it + 1) & 1) * 2 * TILE_B;
      stage_async(P, NROWS, m0, (it + 1) * BK, nA, wave, lane);
      stage_async(hT, NROWS, n0, (it + 1) * BK, nA + TILE_B, wave, lane);
    }
    bf16x8 a[4], b[4];
#pragma unroll
    for (int f = 0; f < 4; ++f) {
      a[f] = *(const bf16x8*)(lA + (wm * 64 + f * 16 + l15) * BK + quad * 8);
      b[f] = *(const bf16x8*)(lB + (wn * 64 + f * 16 + l15) * BK + quad * 8);
    }
#pragma unroll
    for (int i = 0; i < 4; ++i)
#pragma unroll
      for (int j = 0; j < 4; ++j)
        acc[i][j] = __builtin_amdgcn_mfma_f32_16x16x32_bf16(a[i], b[j], acc[i][j], 0, 0, 0);
    __syncthreads();
  }
#pragma unroll
  for (int i = 0; i < 4; ++i) {
    int rbase = m0 + wm * 64 + i * 16 + quad * 4;
#pragma unroll
    for (int r = 0; r < 4; ++r) {
      float rl = __builtin_amdgcn_rcpf(lsum[rbase + r]);
#pragma unroll
      for (int j = 0; j < 4; ++j) {
        int col = n0 + wn * 64 + j * 16 + l15;
        out[(size_t)(rbase + r) * DFEAT + col] = fast_tanh(acc[i][j][r] * rl);
      }
    }
  }
}

extern "C" void kernel_launch(void* const* d_in, const int* in_sizes, int n_in,
                              void* d_out, int out_size, void* d_ws, size_t ws_size,
                              hipStream_t stream) {
  const float* x = (const float*)d_in[0];
  const float* W = (const float*)d_in[1];
  const float* bias = (const float*)d_in[2];
  float* out = (float*)d_out;

  bf16_t* xh = (bf16_t*)d_ws;
  bf16_t* xl = xh + (size_t)NROWS * DFEAT;
  bf16_t* Wh = xl + (size_t)NROWS * DFEAT;
  bf16_t* Wl = Wh + (size_t)DFEAT * DFEAT;
  bf16_t* h  = Wl + (size_t)DFEAT * DFEAT;
  bf16_t* hT = h + (size_t)NROWS * DFEAT;
  float* lsum = (float*)(hT + (size_t)NROWS * DFEAT);
  bf16_t* P = (bf16_t*)(lsum + NROWS);

  split_kernel<<<(NROWS * DFEAT) / 256, 256, 0, stream>>>(x, xh, xl, NROWS * DFEAT);
  split_kernel<<<(DFEAT * DFEAT) / 256, 256, 0, stream>>>(W, Wh, Wl, DFEAT * DFEAT);
  gemm1_kernel<<<dim3(DFEAT / 128, NROWS / 128), 256, 0, stream>>>(xh, xl, Wh, Wl, bias, h);
  transpose_kernel<<<dim3(DFEAT / 64, NROWS / 64), 256, 0, stream>>>(h, hT);
  hipMemsetAsync(lsum, 0, NROWS * sizeof(float), stream);
  scores_sym_kernel<<<NBLK * (NBLK + 1) / 2, 256, 0, stream>>>(h, P, lsum);
  pv_kernel<<<dim3(DFEAT / 128, NROWS / 128), 256, 0, stream>>>(P, hT, lsum, out);
}

// Round 5
// 441.232 us; speedup vs baseline: 1.4002x; 1.2050x over previous
//
#include <hip/hip_runtime.h>
#include <hip/hip_bf16.h>
#include <cstdint>
#include <cstddef>

typedef __bf16 bf16_t;
typedef __bf16 bf16x8 __attribute__((ext_vector_type(8)));
typedef float f32x4 __attribute__((ext_vector_type(4)));

#define NROWS 8192
#define DFEAT 1024
#define BK 32
#define NBLK 64            // NROWS/128
#define TILE_B (128 * BK)  // bf16 elems per staged tile (8 KB)

typedef __attribute__((address_space(3))) unsigned int lds_uint;
typedef __attribute__((address_space(1))) const unsigned int glb_uint;

__device__ __forceinline__ float fast_tanh(float x) {
  float e = __expf(2.0f * x);
  return 1.0f - 2.0f * __builtin_amdgcn_rcpf(e + 1.0f);
}

__global__ __launch_bounds__(256) void split_kernel(const float* __restrict__ in,
                                                    bf16_t* __restrict__ hi,
                                                    bf16_t* __restrict__ lo, int n) {
  int i = blockIdx.x * 256 + threadIdx.x;
  if (i < n) {
    float v = in[i];
    bf16_t h = (bf16_t)v;
    hi[i] = h;
    lo[i] = (bf16_t)(v - (float)h);
  }
}

// Async-stage a 128x32 bf16 tile into contiguous LDS [128][32] via global_load_lds w16.
__device__ __forceinline__ void stage_async(const bf16_t* __restrict__ g, int ld,
                                            int row0, int k0, bf16_t* lds,
                                            int wave, int lane) {
#pragma unroll
  for (int t = 0; t < 2; ++t) {
    const int rb = (t * 4 + wave) * 16;
    const bf16_t* gp = g + (size_t)(row0 + rb + (lane >> 2)) * ld + (k0 + (lane & 3) * 8);
    __builtin_amdgcn_global_load_lds((glb_uint*)gp, (lds_uint*)(lds + rb * BK), 16, 0, 0);
  }
}

// h = x @ W^T + b in split-bf16 (hh + hl + lh), output bf16
__global__ __launch_bounds__(256) void gemm1_kernel(const bf16_t* __restrict__ xh,
                                                    const bf16_t* __restrict__ xl,
                                                    const bf16_t* __restrict__ Wh,
                                                    const bf16_t* __restrict__ Wl,
                                                    const float* __restrict__ bias,
                                                    bf16_t* __restrict__ hout) {
  __shared__ bf16_t lAh[TILE_B], lAl[TILE_B], lBh[TILE_B], lBl[TILE_B];
  const int tid = threadIdx.x;
  const int wave = tid >> 6, lane = tid & 63;
  const int wm = wave >> 1, wn = wave & 1;
  const int l15 = lane & 15, quad = lane >> 4;
  const int m0 = blockIdx.y * 128, n0 = blockIdx.x * 128;
  f32x4 acc[4][4] = {};
  for (int k0 = 0; k0 < DFEAT; k0 += BK) {
    __syncthreads();
    stage_async(xh, DFEAT, m0, k0, lAh, wave, lane);
    stage_async(xl, DFEAT, m0, k0, lAl, wave, lane);
    stage_async(Wh, DFEAT, n0, k0, lBh, wave, lane);
    stage_async(Wl, DFEAT, n0, k0, lBl, wave, lane);
    __syncthreads();
    bf16x8 ah[4], al[4], bh[4], bl[4];
#pragma unroll
    for (int f = 0; f < 4; ++f) {
      int ar = wm * 64 + f * 16 + l15, br = wn * 64 + f * 16 + l15;
      ah[f] = *(const bf16x8*)(lAh + ar * BK + quad * 8);
      al[f] = *(const bf16x8*)(lAl + ar * BK + quad * 8);
      bh[f] = *(const bf16x8*)(lBh + br * BK + quad * 8);
      bl[f] = *(const bf16x8*)(lBl + br * BK + quad * 8);
    }
#pragma unroll
    for (int i = 0; i < 4; ++i)
#pragma unroll
      for (int j = 0; j < 4; ++j) {
        acc[i][j] = __builtin_amdgcn_mfma_f32_16x16x32_bf16(ah[i], bh[j], acc[i][j], 0, 0, 0);
        acc[i][j] = __builtin_amdgcn_mfma_f32_16x16x32_bf16(ah[i], bl[j], acc[i][j], 0, 0, 0);
        acc[i][j] = __builtin_amdgcn_mfma_f32_16x16x32_bf16(al[i], bh[j], acc[i][j], 0, 0, 0);
      }
  }
#pragma unroll
  for (int i = 0; i < 4; ++i) {
    int rbase = m0 + wm * 64 + i * 16 + quad * 4;
#pragma unroll
    for (int j = 0; j < 4; ++j) {
      int col = n0 + wn * 64 + j * 16 + l15;
      float bv = bias[col];
#pragma unroll
      for (int r = 0; r < 4; ++r)
        hout[(size_t)(rbase + r) * DFEAT + col] = (bf16_t)(acc[i][j][r] + bv);
    }
  }
}

__global__ __launch_bounds__(256) void transpose_kernel(const bf16_t* __restrict__ in,
                                                        bf16_t* __restrict__ outT) {
  __shared__ bf16_t tile[64][65];
  int bm = blockIdx.y * 64, bn = blockIdx.x * 64;
  int tid = threadIdx.x;
  int x = tid & 63, y0 = tid >> 6;
#pragma unroll
  for (int i = 0; i < 16; ++i) {
    int r = y0 * 16 + i;
    tile[r][x] = in[(size_t)(bm + r) * DFEAT + bn + x];
  }
  __syncthreads();
#pragma unroll
  for (int i = 0; i < 16; ++i) {
    int r = y0 * 16 + i;
    outT[(size_t)(bn + r) * NROWS + bm + x] = tile[x][r];
  }
}

// Symmetric scores (single-buffered — dbuf regressed on L3-hot h):
// upper-triangular 128x128 tiles of P = exp(tanh(h h^T)); write tile +
// LDS-transposed mirror; fold row-sums and col-sums into lsum.
__global__ __launch_bounds__(256) void scores_sym_kernel(const bf16_t* __restrict__ h,
                                                         bf16_t* __restrict__ P,
                                                         float* __restrict__ lsum) {
  __shared__ __align__(16) char smem[128 * 136 * 2];
  bf16_t* lA = (bf16_t*)smem;
  bf16_t* lB = (bf16_t*)(smem + 128 * BK * 2);
  bf16_t (*mir)[136] = (bf16_t(*)[136])smem;

  int t = blockIdx.x, bm = 0;
  while (t >= NBLK - bm) { t -= NBLK - bm; ++bm; }
  const int bn = bm + t;
  const bool offdiag = (bm != bn);
  const int m0 = bm * 128, n0 = bn * 128;

  const int tid = threadIdx.x;
  const int wave = tid >> 6, lane = tid & 63;
  const int wm = wave >> 1, wn = wave & 1;
  const int l15 = lane & 15, quad = lane >> 4;

  f32x4 acc[4][4] = {};
  for (int k0 = 0; k0 < DFEAT; k0 += BK) {
    __syncthreads();
    stage_async(h, DFEAT, m0, k0, lA, wave, lane);
    stage_async(h, DFEAT, n0, k0, lB, wave, lane);
    __syncthreads();
    bf16x8 a[4], b[4];
#pragma unroll
    for (int f = 0; f < 4; ++f) {
      a[f] = *(const bf16x8*)(lA + (wm * 64 + f * 16 + l15) * BK + quad * 8);
      b[f] = *(const bf16x8*)(lB + (wn * 64 + f * 16 + l15) * BK + quad * 8);
    }
#pragma unroll
    for (int i = 0; i < 4; ++i)
#pragma unroll
      for (int j = 0; j < 4; ++j)
        acc[i][j] = __builtin_amdgcn_mfma_f32_16x16x32_bf16(a[i], b[j], acc[i][j], 0, 0, 0);
  }
  __syncthreads();  // staging reads done; smem now free for mirror tile

  float rs[4][4];
  float cs[4];
#pragma unroll
  for (int i = 0; i < 4; ++i)
#pragma unroll
    for (int r = 0; r < 4; ++r) rs[i][r] = 0.f;
#pragma unroll
  for (int j = 0; j < 4; ++j) cs[j] = 0.f;

#pragma unroll
  for (int i = 0; i < 4; ++i) {
    const int rl_loc = wm * 64 + i * 16 + quad * 4;
    const int rbase = m0 + rl_loc;
#pragma unroll
    for (int j = 0; j < 4; ++j) {
      const int cl_loc = wn * 64 + j * 16 + l15;
      const int col = n0 + cl_loc;
      bf16_t pbv[4];
#pragma unroll
      for (int r = 0; r < 4; ++r) {
        float p = __expf(fast_tanh(acc[i][j][r]));
        pbv[r] = (bf16_t)p;
        rs[i][r] += p;
        cs[j] += p;
        P[(size_t)(rbase + r) * NROWS + col] = pbv[r];
      }
      if (offdiag) __builtin_memcpy(&mir[cl_loc][rl_loc], pbv, 8);
    }
  }

#pragma unroll
  for (int off = 1; off < 16; off <<= 1)
#pragma unroll
    for (int i = 0; i < 4; ++i)
#pragma unroll
      for (int r = 0; r < 4; ++r) rs[i][r] += __shfl_xor(rs[i][r], off, 64);
  if (l15 == 0) {
#pragma unroll
    for (int i = 0; i < 4; ++i) {
      int rbase = m0 + wm * 64 + i * 16 + quad * 4;
#pragma unroll
      for (int r = 0; r < 4; ++r) atomicAdd(&lsum[rbase + r], rs[i][r]);
    }
  }

  if (offdiag) {
#pragma unroll
    for (int off = 16; off < 64; off <<= 1)
#pragma unroll
      for (int j = 0; j < 4; ++j) cs[j] += __shfl_xor(cs[j], off, 64);
    if (quad == 0) {
#pragma unroll
      for (int j = 0; j < 4; ++j)
        atomicAdd(&lsum[n0 + wn * 64 + j * 16 + l15], cs[j]);
    }
    __syncthreads();
#pragma unroll
    for (int it = 0; it < 8; ++it) {
      int q = tid + it * 256;
      int c = q >> 4, r0 = (q & 15) * 8;
      bf16x8 v = *(const bf16x8*)(&mir[c][r0]);
      *(bf16x8*)(P + (size_t)(n0 + c) * NROWS + m0 + r0) = v;
    }
  }
}

// out = tanh((P @ h) / l), hT row-major B operand; double-buffered staging.
// Grid (x=m-blocks=64, y=n-blocks=8): linear id = x + 64y, 64 % 8 == 0, so the
// 8 blocks sharing a P row-strip (same x) map to the same XCD under
// round-robin id%8 assignment -> 2 MB strip served from that XCD's L2.
__global__ __launch_bounds__(256) void pv_kernel(const bf16_t* __restrict__ P,
                                                 const bf16_t* __restrict__ hT,
                                                 const float* __restrict__ lsum,
                                                 float* __restrict__ out) {
  __shared__ __align__(16) bf16_t smem[4 * TILE_B];  // 2 phases x (lA+lB) = 32 KB
  const int tid = threadIdx.x;
  const int wave = tid >> 6, lane = tid & 63;
  const int wm = wave >> 1, wn = wave & 1;
  const int l15 = lane & 15, quad = lane >> 4;
  const int m0 = blockIdx.x * 128, n0 = blockIdx.y * 128;
  f32x4 acc[4][4] = {};
  const int NIT = NROWS / BK;
  stage_async(P, NROWS, m0, 0, smem, wave, lane);
  stage_async(hT, NROWS, n0, 0, smem + TILE_B, wave, lane);
  __syncthreads();
  for (int it = 0; it < NIT; ++it) {
    bf16_t* lA = smem + (it & 1) * 2 * TILE_B;
    bf16_t* lB = lA + TILE_B;
    if (it + 1 < NIT) {
      bf16_t* nA = smem + ((it + 1) & 1) * 2 * TILE_B;
      stage_async(P, NROWS, m0, (it + 1) * BK, nA, wave, lane);
      stage_async(hT, NROWS, n0, (it + 1) * BK, nA + TILE_B, wave, lane);
    }
    bf16x8 a[4], b[4];
#pragma unroll
    for (int f = 0; f < 4; ++f) {
      a[f] = *(const bf16x8*)(lA + (wm * 64 + f * 16 + l15) * BK + quad * 8);
      b[f] = *(const bf16x8*)(lB + (wn * 64 + f * 16 + l15) * BK + quad * 8);
    }
#pragma unroll
    for (int i = 0; i < 4; ++i)
#pragma unroll
      for (int j = 0; j < 4; ++j)
        acc[i][j] = __builtin_amdgcn_mfma_f32_16x16x32_bf16(a[i], b[j], acc[i][j], 0, 0, 0);
    __syncthreads();
  }
#pragma unroll
  for (int i = 0; i < 4; ++i) {
    int rbase = m0 + wm * 64 + i * 16 + quad * 4;
#pragma unroll
    for (int r = 0; r < 4; ++r) {
      float rl = __builtin_amdgcn_rcpf(lsum[rbase + r]);
#pragma unroll
      for (int j = 0; j < 4; ++j) {
        int col = n0 + wn * 64 + j * 16 + l15;
        out[(size_t)(rbase + r) * DFEAT + col] = fast_tanh(acc[i][j][r] * rl);
      }
    }
  }
}

extern "C" void kernel_launch(void* const* d_in, const int* in_sizes, int n_in,
                              void* d_out, int out_size, void* d_ws, size_t ws_size,
                              hipStream_t stream) {
  const float* x = (const float*)d_in[0];
  const float* W = (const float*)d_in[1];
  const float* bias = (const float*)d_in[2];
  float* out = (float*)d_out;

  bf16_t* xh = (bf16_t*)d_ws;
  bf16_t* xl = xh + (size_t)NROWS * DFEAT;
  bf16_t* Wh = xl + (size_t)NROWS * DFEAT;
  bf16_t* Wl = Wh + (size_t)DFEAT * DFEAT;
  bf16_t* h  = Wl + (size_t)DFEAT * DFEAT;
  bf16_t* hT = h + (size_t)NROWS * DFEAT;
  float* lsum = (float*)(hT + (size_t)NROWS * DFEAT);
  bf16_t* P = (bf16_t*)(lsum + NROWS);

  split_kernel<<<(NROWS * DFEAT) / 256, 256, 0, stream>>>(x, xh, xl, NROWS * DFEAT);
  split_kernel<<<(DFEAT * DFEAT) / 256, 256, 0, stream>>>(W, Wh, Wl, DFEAT * DFEAT);
  gemm1_kernel<<<dim3(DFEAT / 128, NROWS / 128), 256, 0, stream>>>(xh, xl, Wh, Wl, bias, h);
  transpose_kernel<<<dim3(DFEAT / 64, NROWS / 64), 256, 0, stream>>>(h, hT);
  hipMemsetAsync(lsum, 0, NROWS * sizeof(float), stream);
  scores_sym_kernel<<<NBLK * (NBLK + 1) / 2, 256, 0, stream>>>(h, P, lsum);
  pv_kernel<<<dim3(NROWS / 128, DFEAT / 128), 256, 0, stream>>>(P, hT, lsum, out);
}

// Round 6
// 405.943 us; speedup vs baseline: 1.5219x; 1.0869x over previous
//
#include <hip/hip_runtime.h>
#include <hip/hip_bf16.h>
#include <cstdint>
#include <cstddef>

typedef __bf16 bf16_t;
typedef __bf16 bf16x4 __attribute__((ext_vector_type(4)));
typedef __bf16 bf16x8 __attribute__((ext_vector_type(8)));
typedef float f32x4 __attribute__((ext_vector_type(4)));

#define NROWS 8192
#define DFEAT 1024
#define BK 32
#define NBLK 64            // NROWS/128
#define TILE_B (128 * BK)  // bf16 elems per staged tile (8 KB)

typedef __attribute__((address_space(3))) unsigned int lds_uint;
typedef __attribute__((address_space(1))) const unsigned int glb_uint;

__device__ __forceinline__ float fast_tanh(float x) {
  float e = __expf(2.0f * x);
  return 1.0f - 2.0f * __builtin_amdgcn_rcpf(e + 1.0f);
}

__global__ __launch_bounds__(256) void cast_kernel(const float* __restrict__ in,
                                                   bf16_t* __restrict__ out, int n4) {
  int i = blockIdx.x * 256 + threadIdx.x;
  if (i < n4) {
    float4 v = *(const float4*)(in + i * 4);
    bf16x4 o = {(bf16_t)v.x, (bf16_t)v.y, (bf16_t)v.z, (bf16_t)v.w};
    *(bf16x4*)(out + i * 4) = o;
  }
}

// Async-stage a 128x32 bf16 tile into contiguous LDS [128][32] via global_load_lds w16.
__device__ __forceinline__ void stage_async(const bf16_t* __restrict__ g, int ld,
                                            int row0, int k0, bf16_t* lds,
                                            int wave, int lane) {
#pragma unroll
  for (int t = 0; t < 2; ++t) {
    const int rb = (t * 4 + wave) * 16;
    const bf16_t* gp = g + (size_t)(row0 + rb + (lane >> 2)) * ld + (k0 + (lane & 3) * 8);
    __builtin_amdgcn_global_load_lds((glb_uint*)gp, (lds_uint*)(lds + rb * BK), 16, 0, 0);
  }
}

// h = x @ W^T + b, plain bf16, double-buffered; writes h AND hT.
// Grid (x=m=64, y=n=8): same-m0 blocks land on one XCD -> x-strip L2 reuse.
__global__ __launch_bounds__(256) void gemm1_kernel(const bf16_t* __restrict__ xb,
                                                    const bf16_t* __restrict__ Wb,
                                                    const float* __restrict__ bias,
                                                    bf16_t* __restrict__ hout,
                                                    bf16_t* __restrict__ hT) {
  __shared__ __align__(16) bf16_t smem[4 * TILE_B];  // 2 phases x (lA+lB) = 32 KB
  const int tid = threadIdx.x;
  const int wave = tid >> 6, lane = tid & 63;
  const int wm = wave >> 1, wn = wave & 1;
  const int l15 = lane & 15, quad = lane >> 4;
  const int m0 = blockIdx.x * 128, n0 = blockIdx.y * 128;
  f32x4 acc[4][4] = {};
  const int NIT = DFEAT / BK;
  stage_async(xb, DFEAT, m0, 0, smem, wave, lane);
  stage_async(Wb, DFEAT, n0, 0, smem + TILE_B, wave, lane);
  __syncthreads();
  for (int it = 0; it < NIT; ++it) {
    bf16_t* lA = smem + (it & 1) * 2 * TILE_B;
    bf16_t* lB = lA + TILE_B;
    if (it + 1 < NIT) {
      bf16_t* nA = smem + ((it + 1) & 1) * 2 * TILE_B;
      stage_async(xb, DFEAT, m0, (it + 1) * BK, nA, wave, lane);
      stage_async(Wb, DFEAT, n0, (it + 1) * BK, nA + TILE_B, wave, lane);
    }
    bf16x8 a[4], b[4];
#pragma unroll
    for (int f = 0; f < 4; ++f) {
      a[f] = *(const bf16x8*)(lA + (wm * 64 + f * 16 + l15) * BK + quad * 8);
      b[f] = *(const bf16x8*)(lB + (wn * 64 + f * 16 + l15) * BK + quad * 8);
    }
#pragma unroll
    for (int i = 0; i < 4; ++i)
#pragma unroll
      for (int j = 0; j < 4; ++j)
        acc[i][j] = __builtin_amdgcn_mfma_f32_16x16x32_bf16(a[i], b[j], acc[i][j], 0, 0, 0);
    __syncthreads();
  }
#pragma unroll
  for (int i = 0; i < 4; ++i) {
    int rbase = m0 + wm * 64 + i * 16 + quad * 4;
#pragma unroll
    for (int j = 0; j < 4; ++j) {
      int col = n0 + wn * 64 + j * 16 + l15;
      float bv = bias[col];
      bf16x4 hv;
#pragma unroll
      for (int r = 0; r < 4; ++r) hv[r] = (bf16_t)(acc[i][j][r] + bv);
#pragma unroll
      for (int r = 0; r < 4; ++r)
        hout[(size_t)(rbase + r) * DFEAT + col] = hv[r];
      *(bf16x4*)(hT + (size_t)col * NROWS + rbase) = hv;  // fused transpose (8-B store)
    }
  }
}

// Symmetric scores (single-buffered — dbuf regressed on L3-hot h):
// upper-triangular 128x128 tiles of P = exp(tanh(h h^T)); write tile +
// LDS-transposed mirror; fold row-sums and col-sums into lsum.
__global__ __launch_bounds__(256) void scores_sym_kernel(const bf16_t* __restrict__ h,
                                                         bf16_t* __restrict__ P,
                                                         float* __restrict__ lsum) {
  __shared__ __align__(16) char smem[128 * 136 * 2];
  bf16_t* lA = (bf16_t*)smem;
  bf16_t* lB = (bf16_t*)(smem + 128 * BK * 2);
  bf16_t (*mir)[136] = (bf16_t(*)[136])smem;

  int t = blockIdx.x, bm = 0;
  while (t >= NBLK - bm) { t -= NBLK - bm; ++bm; }
  const int bn = bm + t;
  const bool offdiag = (bm != bn);
  const int m0 = bm * 128, n0 = bn * 128;

  const int tid = threadIdx.x;
  const int wave = tid >> 6, lane = tid & 63;
  const int wm = wave >> 1, wn = wave & 1;
  const int l15 = lane & 15, quad = lane >> 4;

  f32x4 acc[4][4] = {};
  for (int k0 = 0; k0 < DFEAT; k0 += BK) {
    __syncthreads();
    stage_async(h, DFEAT, m0, k0, lA, wave, lane);
    stage_async(h, DFEAT, n0, k0, lB, wave, lane);
    __syncthreads();
    bf16x8 a[4], b[4];
#pragma unroll
    for (int f = 0; f < 4; ++f) {
      a[f] = *(const bf16x8*)(lA + (wm * 64 + f * 16 + l15) * BK + quad * 8);
      b[f] = *(const bf16x8*)(lB + (wn * 64 + f * 16 + l15) * BK + quad * 8);
    }
#pragma unroll
    for (int i = 0; i < 4; ++i)
#pragma unroll
      for (int j = 0; j < 4; ++j)
        acc[i][j] = __builtin_amdgcn_mfma_f32_16x16x32_bf16(a[i], b[j], acc[i][j], 0, 0, 0);
  }
  __syncthreads();  // staging reads done; smem now free for mirror tile

  float rs[4][4];
  float cs[4];
#pragma unroll
  for (int i = 0; i < 4; ++i)
#pragma unroll
    for (int r = 0; r < 4; ++r) rs[i][r] = 0.f;
#pragma unroll
  for (int j = 0; j < 4; ++j) cs[j] = 0.f;

#pragma unroll
  for (int i = 0; i < 4; ++i) {
    const int rl_loc = wm * 64 + i * 16 + quad * 4;
    const int rbase = m0 + rl_loc;
#pragma unroll
    for (int j = 0; j < 4; ++j) {
      const int cl_loc = wn * 64 + j * 16 + l15;
      const int col = n0 + cl_loc;
      bf16_t pbv[4];
#pragma unroll
      for (int r = 0; r < 4; ++r) {
        float p = __expf(fast_tanh(acc[i][j][r]));
        pbv[r] = (bf16_t)p;
        rs[i][r] += p;
        cs[j] += p;
        P[(size_t)(rbase + r) * NROWS + col] = pbv[r];
      }
      if (offdiag) __builtin_memcpy(&mir[cl_loc][rl_loc], pbv, 8);
    }
  }

#pragma unroll
  for (int off = 1; off < 16; off <<= 1)
#pragma unroll
    for (int i = 0; i < 4; ++i)
#pragma unroll
      for (int r = 0; r < 4; ++r) rs[i][r] += __shfl_xor(rs[i][r], off, 64);
  if (l15 == 0) {
#pragma unroll
    for (int i = 0; i < 4; ++i) {
      int rbase = m0 + wm * 64 + i * 16 + quad * 4;
#pragma unroll
      for (int r = 0; r < 4; ++r) atomicAdd(&lsum[rbase + r], rs[i][r]);
    }
  }

  if (offdiag) {
#pragma unroll
    for (int off = 16; off < 64; off <<= 1)
#pragma unroll
      for (int j = 0; j < 4; ++j) cs[j] += __shfl_xor(cs[j], off, 64);
    if (quad == 0) {
#pragma unroll
      for (int j = 0; j < 4; ++j)
        atomicAdd(&lsum[n0 + wn * 64 + j * 16 + l15], cs[j]);
    }
    __syncthreads();
#pragma unroll
    for (int it = 0; it < 8; ++it) {
      int q = tid + it * 256;
      int c = q >> 4, r0 = (q & 15) * 8;
      bf16x8 v = *(const bf16x8*)(&mir[c][r0]);
      *(bf16x8*)(P + (size_t)(n0 + c) * NROWS + m0 + r0) = v;
    }
  }
}

// out = tanh((P @ h) / l), hT row-major B operand; double-buffered staging.
// Grid (x=m=64, y=n=8): same-m0 blocks share one XCD -> P strip L2-resident.
__global__ __launch_bounds__(256) void pv_kernel(const bf16_t* __restrict__ P,
                                                 const bf16_t* __restrict__ hT,
                                                 const float* __restrict__ lsum,
                                                 float* __restrict__ out) {
  __shared__ __align__(16) bf16_t smem[4 * TILE_B];  // 2 phases x (lA+lB) = 32 KB
  const int tid = threadIdx.x;
  const int wave = tid >> 6, lane = tid & 63;
  const int wm = wave >> 1, wn = wave & 1;
  const int l15 = lane & 15, quad = lane >> 4;
  const int m0 = blockIdx.x * 128, n0 = blockIdx.y * 128;
  f32x4 acc[4][4] = {};
  const int NIT = NROWS / BK;
  stage_async(P, NROWS, m0, 0, smem, wave, lane);
  stage_async(hT, NROWS, n0, 0, smem + TILE_B, wave, lane);
  __syncthreads();
  for (int it = 0; it < NIT; ++it) {
    bf16_t* lA = smem + (it & 1) * 2 * TILE_B;
    bf16_t* lB = lA + TILE_B;
    if (it + 1 < NIT) {
      bf16_t* nA = smem + ((it + 1) & 1) * 2 * TILE_B;
      stage_async(P, NROWS, m0, (it + 1) * BK, nA, wave, lane);
      stage_async(hT, NROWS, n0, (it + 1) * BK, nA + TILE_B, wave, lane);
    }
    bf16x8 a[4], b[4];
#pragma unroll
    for (int f = 0; f < 4; ++f) {
      a[f] = *(const bf16x8*)(lA + (wm * 64 + f * 16 + l15) * BK + quad * 8);
      b[f] = *(const bf16x8*)(lB + (wn * 64 + f * 16 + l15) * BK + quad * 8);
    }
#pragma unroll
    for (int i = 0; i < 4; ++i)
#pragma unroll
      for (int j = 0; j < 4; ++j)
        acc[i][j] = __builtin_amdgcn_mfma_f32_16x16x32_bf16(a[i], b[j], acc[i][j], 0, 0, 0);
    __syncthreads();
  }
#pragma unroll
  for (int i = 0; i < 4; ++i) {
    int rbase = m0 + wm * 64 + i * 16 + quad * 4;
#pragma unroll
    for (int r = 0; r < 4; ++r) {
      float rl = __builtin_amdgcn_rcpf(lsum[rbase + r]);
#pragma unroll
      for (int j = 0; j < 4; ++j) {
        int col = n0 + wn * 64 + j * 16 + l15;
        out[(size_t)(rbase + r) * DFEAT + col] = fast_tanh(acc[i][j][r] * rl);
      }
    }
  }
}

extern "C" void kernel_launch(void* const* d_in, const int* in_sizes, int n_in,
                              void* d_out, int out_size, void* d_ws, size_t ws_size,
                              hipStream_t stream) {
  const float* x = (const float*)d_in[0];
  const float* W = (const float*)d_in[1];
  const float* bias = (const float*)d_in[2];
  float* out = (float*)d_out;

  bf16_t* xb = (bf16_t*)d_ws;                        // 16 MB
  bf16_t* Wb = xb + (size_t)NROWS * DFEAT;           // 2 MB
  bf16_t* h  = Wb + (size_t)DFEAT * DFEAT;           // 16 MB
  bf16_t* hT = h + (size_t)NROWS * DFEAT;            // 16 MB
  float* lsum = (float*)(hT + (size_t)NROWS * DFEAT);
  bf16_t* P = (bf16_t*)(lsum + NROWS);               // 134 MB

  cast_kernel<<<(NROWS * DFEAT / 4) / 256, 256, 0, stream>>>(x, xb, NROWS * DFEAT / 4);
  cast_kernel<<<(DFEAT * DFEAT / 4) / 256, 256, 0, stream>>>(W, Wb, DFEAT * DFEAT / 4);
  gemm1_kernel<<<dim3(NROWS / 128, DFEAT / 128), 256, 0, stream>>>(xb, Wb, bias, h, hT);
  hipMemsetAsync(lsum, 0, NROWS * sizeof(float), stream);
  scores_sym_kernel<<<NBLK * (NBLK + 1) / 2, 256, 0, stream>>>(h, P, lsum);
  pv_kernel<<<dim3(NROWS / 128, DFEAT / 128), 256, 0, stream>>>(P, hT, lsum, out);
}

// Round 7
// 319.901 us; speedup vs baseline: 1.9313x; 1.2690x over previous
//
#include <hip/hip_runtime.h>
#include <hip/hip_bf16.h>
#include <cstdint>
#include <cstddef>

typedef __bf16 bf16_t;
typedef __bf16 bf16x4 __attribute__((ext_vector_type(4)));
typedef __bf16 bf16x8 __attribute__((ext_vector_type(8)));
typedef float f32x4 __attribute__((ext_vector_type(4)));
typedef float f32x16 __attribute__((ext_vector_type(16)));
typedef float f32x2 __attribute__((ext_vector_type(2)));
typedef int i32x4 __attribute__((ext_vector_type(4)));
typedef int i32x8 __attribute__((ext_vector_type(8)));

#define NROWS 8192
#define DFEAT 1024
#define BK 32
#define NBLK 64            // NROWS/128
#define TILE_B (128 * BK)  // bf16 elems per staged tile (8 KB)
#define F8TILE 8192        // fp8 bytes per staged 128x64 tile

typedef __attribute__((address_space(3))) unsigned int lds_uint;
typedef __attribute__((address_space(1))) const unsigned int glb_uint;

__device__ __forceinline__ float fast_tanh(float x) {
  float e = __expf(2.0f * x);
  return 1.0f - 2.0f * __builtin_amdgcn_rcpf(e + 1.0f);
}

// pack 4 floats -> 4 fp8 e4m3 bytes (OCP, HW cvt)
__device__ __forceinline__ unsigned pack_fp8x4(float a, float b, float c, float d) {
  unsigned v = 0;
  v = __builtin_amdgcn_cvt_pk_fp8_f32(a, b, v, false);
  v = __builtin_amdgcn_cvt_pk_fp8_f32(c, d, v, true);
  return v;
}

__global__ __launch_bounds__(256) void cast_kernel(const float* __restrict__ in,
                                                   bf16_t* __restrict__ out, int n4) {
  int i = blockIdx.x * 256 + threadIdx.x;
  if (i < n4) {
    float4 v = *(const float4*)(in + i * 4);
    bf16x4 o = {(bf16_t)v.x, (bf16_t)v.y, (bf16_t)v.z, (bf16_t)v.w};
    *(bf16x4*)(out + i * 4) = o;
  }
}

// Async-stage a 128x32 bf16 tile into contiguous LDS [128][32] via global_load_lds w16.
__device__ __forceinline__ void stage_async(const bf16_t* __restrict__ g, int ld,
                                            int row0, int k0, bf16_t* lds,
                                            int wave, int lane) {
#pragma unroll
  for (int t = 0; t < 2; ++t) {
    const int rb = (t * 4 + wave) * 16;
    const bf16_t* gp = g + (size_t)(row0 + rb + (lane >> 2)) * ld + (k0 + (lane & 3) * 8);
    __builtin_amdgcn_global_load_lds((glb_uint*)gp, (lds_uint*)(lds + rb * BK), 16, 0, 0);
  }
}

// Async-stage a 128x64 fp8 tile into contiguous LDS [128][64B] (row stride 64B).
__device__ __forceinline__ void stage_f8(const uint8_t* __restrict__ g, int ld,
                                         int row0, int k0, uint8_t* lds,
                                         int wave, int lane) {
#pragma unroll
  for (int t = 0; t < 2; ++t) {
    const int rb = (t * 4 + wave) * 16;
    const uint8_t* gp = g + (size_t)(row0 + rb + (lane >> 2)) * ld + (k0 + (lane & 3) * 16);
    __builtin_amdgcn_global_load_lds((glb_uint*)gp, (lds_uint*)(lds + rb * 64), 16, 0, 0);
  }
}

// h = x @ W^T + b, bf16, double-buffered; writes h (bf16, for scores) AND
// hT (fp8 e4m3, consumed only by the MX-fp8 pv kernel).
__global__ __launch_bounds__(256) void gemm1_kernel(const bf16_t* __restrict__ xb,
                                                    const bf16_t* __restrict__ Wb,
                                                    const float* __restrict__ bias,
                                                    bf16_t* __restrict__ hout,
                                                    uint8_t* __restrict__ hT8) {
  __shared__ __align__(16) bf16_t smem[4 * TILE_B];
  const int tid = threadIdx.x;
  const int wave = tid >> 6, lane = tid & 63;
  const int wm = wave >> 1, wn = wave & 1;
  const int l15 = lane & 15, quad = lane >> 4;
  const int m0 = blockIdx.x * 128, n0 = blockIdx.y * 128;
  f32x4 acc[4][4] = {};
  const int NIT = DFEAT / BK;
  stage_async(xb, DFEAT, m0, 0, smem, wave, lane);
  stage_async(Wb, DFEAT, n0, 0, smem + TILE_B, wave, lane);
  __syncthreads();
  for (int it = 0; it < NIT; ++it) {
    bf16_t* lA = smem + (it & 1) * 2 * TILE_B;
    bf16_t* lB = lA + TILE_B;
    if (it + 1 < NIT) {
      bf16_t* nA = smem + ((it + 1) & 1) * 2 * TILE_B;
      stage_async(xb, DFEAT, m0, (it + 1) * BK, nA, wave, lane);
      stage_async(Wb, DFEAT, n0, (it + 1) * BK, nA + TILE_B, wave, lane);
    }
    bf16x8 a[4], b[4];
#pragma unroll
    for (int f = 0; f < 4; ++f) {
      a[f] = *(const bf16x8*)(lA + (wm * 64 + f * 16 + l15) * BK + quad * 8);
      b[f] = *(const bf16x8*)(lB + (wn * 64 + f * 16 + l15) * BK + quad * 8);
    }
#pragma unroll
    for (int i = 0; i < 4; ++i)
#pragma unroll
      for (int j = 0; j < 4; ++j)
        acc[i][j] = __builtin_amdgcn_mfma_f32_16x16x32_bf16(a[i], b[j], acc[i][j], 0, 0, 0);
    __syncthreads();
  }
#pragma unroll
  for (int i = 0; i < 4; ++i) {
    int rbase = m0 + wm * 64 + i * 16 + quad * 4;
#pragma unroll
    for (int j = 0; j < 4; ++j) {
      int col = n0 + wn * 64 + j * 16 + l15;
      float bv = bias[col];
      float hv[4];
#pragma unroll
      for (int r = 0; r < 4; ++r) hv[r] = acc[i][j][r] + bv;
#pragma unroll
      for (int r = 0; r < 4; ++r)
        hout[(size_t)(rbase + r) * DFEAT + col] = (bf16_t)hv[r];
      *(unsigned*)(hT8 + (size_t)col * NROWS + rbase) =
          pack_fp8x4(hv[0], hv[1], hv[2], hv[3]);  // fused transpose, fp8
    }
  }
}

// Symmetric scores (single-buffered; bf16 MFMA — fp8 h here would 10x the
// score error): upper-triangular 128x128 tiles of P = exp(tanh(h h^T)),
// quantized to fp8 e4m3; row-sums and col-sums from the QUANTIZED values.
__global__ __launch_bounds__(256) void scores_sym_kernel(const bf16_t* __restrict__ h,
                                                         uint8_t* __restrict__ P,
                                                         float* __restrict__ lsum) {
  __shared__ __align__(16) char smem[128 * 144];  // staging 16KB / mirror 18KB overlay
  bf16_t* lA = (bf16_t*)smem;
  bf16_t* lB = (bf16_t*)(smem + 128 * BK * 2);
  uint8_t (*mir)[144] = (uint8_t(*)[144])smem;

  int t = blockIdx.x, bm = 0;
  while (t >= NBLK - bm) { t -= NBLK - bm; ++bm; }
  const int bn = bm + t;
  const bool offdiag = (bm != bn);
  const int m0 = bm * 128, n0 = bn * 128;

  const int tid = threadIdx.x;
  const int wave = tid >> 6, lane = tid & 63;
  const int wm = wave >> 1, wn = wave & 1;
  const int l15 = lane & 15, quad = lane >> 4;

  f32x4 acc[4][4] = {};
  for (int k0 = 0; k0 < DFEAT; k0 += BK) {
    __syncthreads();
    stage_async(h, DFEAT, m0, k0, lA, wave, lane);
    stage_async(h, DFEAT, n0, k0, lB, wave, lane);
    __syncthreads();
    bf16x8 a[4], b[4];
#pragma unroll
    for (int f = 0; f < 4; ++f) {
      a[f] = *(const bf16x8*)(lA + (wm * 64 + f * 16 + l15) * BK + quad * 8);
      b[f] = *(const bf16x8*)(lB + (wn * 64 + f * 16 + l15) * BK + quad * 8);
    }
#pragma unroll
    for (int i = 0; i < 4; ++i)
#pragma unroll
      for (int j = 0; j < 4; ++j)
        acc[i][j] = __builtin_amdgcn_mfma_f32_16x16x32_bf16(a[i], b[j], acc[i][j], 0, 0, 0);
  }
  __syncthreads();  // staging reads done; smem now free for mirror tile

  float rs[4][4];
  float cs[4];
#pragma unroll
  for (int i = 0; i < 4; ++i)
#pragma unroll
    for (int r = 0; r < 4; ++r) rs[i][r] = 0.f;
#pragma unroll
  for (int j = 0; j < 4; ++j) cs[j] = 0.f;

#pragma unroll
  for (int i = 0; i < 4; ++i) {
    const int rl_loc = wm * 64 + i * 16 + quad * 4;
    const int rbase = m0 + rl_loc;
#pragma unroll
    for (int j = 0; j < 4; ++j) {
      const int cl_loc = wn * 64 + j * 16 + l15;
      const int col = n0 + cl_loc;
      float p[4];
#pragma unroll
      for (int r = 0; r < 4; ++r) p[r] = __expf(fast_tanh(acc[i][j][r]));
      unsigned packed = pack_fp8x4(p[0], p[1], p[2], p[3]);
      // dequantize for sums so the softmax denominator matches stored P
      f32x2 d0 = __builtin_amdgcn_cvt_pk_f32_fp8(packed, false);
      f32x2 d1 = __builtin_amdgcn_cvt_pk_f32_fp8(packed, true);
      float q[4] = {d0.x, d0.y, d1.x, d1.y};
#pragma unroll
      for (int r = 0; r < 4; ++r) {
        rs[i][r] += q[r];
        cs[j] += q[r];
        P[(size_t)(rbase + r) * NROWS + col] = (uint8_t)(packed >> (8 * r));
      }
      if (offdiag) *(unsigned*)&mir[cl_loc][rl_loc] = packed;
    }
  }

#pragma unroll
  for (int off = 1; off < 16; off <<= 1)
#pragma unroll
    for (int i = 0; i < 4; ++i)
#pragma unroll
      for (int r = 0; r < 4; ++r) rs[i][r] += __shfl_xor(rs[i][r], off, 64);
  if (l15 == 0) {
#pragma unroll
    for (int i = 0; i < 4; ++i) {
      int rbase = m0 + wm * 64 + i * 16 + quad * 4;
#pragma unroll
      for (int r = 0; r < 4; ++r) atomicAdd(&lsum[rbase + r], rs[i][r]);
    }
  }

  if (offdiag) {
#pragma unroll
    for (int off = 16; off < 64; off <<= 1)
#pragma unroll
      for (int j = 0; j < 4; ++j) cs[j] += __shfl_xor(cs[j], off, 64);
    if (quad == 0) {
#pragma unroll
      for (int j = 0; j < 4; ++j)
        atomicAdd(&lsum[n0 + wn * 64 + j * 16 + l15], cs[j]);
    }
    __syncthreads();
#pragma unroll
    for (int it = 0; it < 4; ++it) {
      int q = tid + it * 256;          // 0..1023
      int c = q >> 3, r0 = (q & 7) * 16;
      uint4 v = *(const uint4*)(&mir[c][r0]);
      *(uint4*)(P + (size_t)(n0 + c) * NROWS + m0 + r0) = v;
    }
  }
}

// out = tanh((P @ h) / l): MX-fp8 (e4m3) MFMA with unity scales, K=64/iter,
// double-buffered staging. Grid (x=m=64, y=n=8) keeps same-m0 blocks on one
// XCD -> P strip L2-resident.
__global__ __launch_bounds__(256) void pv_kernel(const uint8_t* __restrict__ P,
                                                 const uint8_t* __restrict__ hT8,
                                                 const float* __restrict__ lsum,
                                                 float* __restrict__ out) {
  __shared__ __align__(16) uint8_t smem[4 * F8TILE];  // 2 phases x (A 8KB + B 8KB)
  const int tid = threadIdx.x;
  const int wave = tid >> 6, lane = tid & 63;
  const int wm = wave >> 1, wn = wave & 1;
  const int l31 = lane & 31, khalf = lane >> 5;
  const int m0 = blockIdx.x * 128, n0 = blockIdx.y * 128;
  f32x16 acc[2][2] = {};
  const int NIT = NROWS / 64;
  stage_f8(P, NROWS, m0, 0, smem, wave, lane);
  stage_f8(hT8, NROWS, n0, 0, smem + F8TILE, wave, lane);
  __syncthreads();
  for (int it = 0; it < NIT; ++it) {
    uint8_t* lA = smem + (it & 1) * 2 * F8TILE;
    uint8_t* lB = lA + F8TILE;
    if (it + 1 < NIT) {
      uint8_t* nA = smem + ((it + 1) & 1) * 2 * F8TILE;
      stage_f8(P, NROWS, m0, (it + 1) * 64, nA, wave, lane);
      stage_f8(hT8, NROWS, n0, (it + 1) * 64, nA + F8TILE, wave, lane);
    }
    i32x8 a[2], b[2];
#pragma unroll
    for (int f = 0; f < 2; ++f) {
      {
        int off = (wm * 64 + f * 32 + l31) * 64 + khalf * 32;
        i32x4 lo = *(const i32x4*)(lA + off);
        i32x4 hi = *(const i32x4*)(lA + off + 16);
        a[f] = i32x8{lo[0], lo[1], lo[2], lo[3], hi[0], hi[1], hi[2], hi[3]};
      }
      {
        int off = (wn * 64 + f * 32 + l31) * 64 + khalf * 32;
        i32x4 lo = *(const i32x4*)(lB + off);
        i32x4 hi = *(const i32x4*)(lB + off + 16);
        b[f] = i32x8{lo[0], lo[1], lo[2], lo[3], hi[0], hi[1], hi[2], hi[3]};
      }
    }
#pragma unroll
    for (int bi = 0; bi < 2; ++bi)
#pragma unroll
      for (int bj = 0; bj < 2; ++bj)
        acc[bi][bj] = __builtin_amdgcn_mfma_scale_f32_32x32x64_f8f6f4(
            a[bi], b[bj], acc[bi][bj], 0, 0, 0, 0x7F7F7F7F, 0, 0x7F7F7F7F);
    __syncthreads();
  }
  // C/D 32x32: col = lane&31, row = (reg&3) + 8*(reg>>2) + 4*(lane>>5)
#pragma unroll
  for (int bi = 0; bi < 2; ++bi)
#pragma unroll
    for (int bj = 0; bj < 2; ++bj) {
      int cbase = n0 + wn * 64 + bj * 32 + l31;
#pragma unroll
      for (int reg = 0; reg < 16; ++reg) {
        int row = m0 + wm * 64 + bi * 32 + (reg & 3) + 8 * (reg >> 2) + 4 * khalf;
        float rl = __builtin_amdgcn_rcpf(lsum[row]);
        out[(size_t)row * DFEAT + cbase] = fast_tanh(acc[bi][bj][reg] * rl);
      }
    }
}

extern "C" void kernel_launch(void* const* d_in, const int* in_sizes, int n_in,
                              void* d_out, int out_size, void* d_ws, size_t ws_size,
                              hipStream_t stream) {
  const float* x = (const float*)d_in[0];
  const float* W = (const float*)d_in[1];
  const float* bias = (const float*)d_in[2];
  float* out = (float*)d_out;

  bf16_t* xb = (bf16_t*)d_ws;                        // 16 MB
  bf16_t* Wb = xb + (size_t)NROWS * DFEAT;           // 2 MB
  bf16_t* h  = Wb + (size_t)DFEAT * DFEAT;           // 16 MB
  uint8_t* hT8 = (uint8_t*)(h + (size_t)NROWS * DFEAT);  // 8 MB (fp8)
  float* lsum = (float*)(hT8 + (size_t)DFEAT * NROWS);
  uint8_t* P = (uint8_t*)(lsum + NROWS);             // 67 MB (fp8)

  cast_kernel<<<(NROWS * DFEAT / 4) / 256, 256, 0, stream>>>(x, xb, NROWS * DFEAT / 4);
  cast_kernel<<<(DFEAT * DFEAT / 4) / 256, 256, 0, stream>>>(W, Wb, DFEAT * DFEAT / 4);
  gemm1_kernel<<<dim3(NROWS / 128, DFEAT / 128), 256, 0, stream>>>(xb, Wb, bias, h, hT8);
  hipMemsetAsync(lsum, 0, NROWS * sizeof(float), stream);
  scores_sym_kernel<<<NBLK * (NBLK + 1) / 2, 256, 0, stream>>>(h, P, lsum);
  pv_kernel<<<dim3(NROWS / 128, DFEAT / 128), 256, 0, stream>>>(P, hT8, lsum, out);
}

// Round 9
// 310.857 us; speedup vs baseline: 1.9875x; 1.0291x over previous
//
#include <hip/hip_runtime.h>
#include <hip/hip_bf16.h>
#include <cstdint>
#include <cstddef>

typedef __bf16 bf16_t;
typedef __bf16 bf16x4 __attribute__((ext_vector_type(4)));
typedef __bf16 bf16x8 __attribute__((ext_vector_type(8)));
typedef float f32x4 __attribute__((ext_vector_type(4)));
typedef float f32x16 __attribute__((ext_vector_type(16)));
typedef float f32x2 __attribute__((ext_vector_type(2)));
typedef int i32x4 __attribute__((ext_vector_type(4)));
typedef int i32x8 __attribute__((ext_vector_type(8)));

#define NROWS 8192
#define DFEAT 1024
#define BK 32
#define NBLK 64            // NROWS/128
#define TILE_B (128 * BK)  // bf16 elems per staged tile (8 KB)
#define F8TILE 8192        // fp8 bytes per staged 128x64 tile
#define NTRI (NBLK * (NBLK + 1) / 2)  // 2080 triangular tiles

typedef __attribute__((address_space(3))) unsigned int lds_uint;
typedef __attribute__((address_space(1))) const unsigned int glb_uint;

__device__ __forceinline__ float fast_tanh(float x) {
  float e = __expf(2.0f * x);
  return 1.0f - 2.0f * __builtin_amdgcn_rcpf(e + 1.0f);
}

// pack 4 floats -> 4 fp8 e4m3 bytes (OCP, HW cvt)
__device__ __forceinline__ unsigned pack_fp8x4(float a, float b, float c, float d) {
  unsigned v = 0;
  v = __builtin_amdgcn_cvt_pk_fp8_f32(a, b, v, false);
  v = __builtin_amdgcn_cvt_pk_fp8_f32(c, d, v, true);
  return v;
}

__global__ __launch_bounds__(256) void cast_kernel(const float* __restrict__ in,
                                                   bf16_t* __restrict__ out, int n4) {
  int i = blockIdx.x * 256 + threadIdx.x;
  if (i < n4) {
    float4 v = *(const float4*)(in + i * 4);
    bf16x4 o = {(bf16_t)v.x, (bf16_t)v.y, (bf16_t)v.z, (bf16_t)v.w};
    *(bf16x4*)(out + i * 4) = o;
  }
}

// Async-stage a 128x32 bf16 tile into contiguous LDS [128][32] via global_load_lds w16.
__device__ __forceinline__ void stage_async(const bf16_t* __restrict__ g, int ld,
                                            int row0, int k0, bf16_t* lds,
                                            int wave, int lane) {
#pragma unroll
  for (int t = 0; t < 2; ++t) {
    const int rb = (t * 4 + wave) * 16;
    const bf16_t* gp = g + (size_t)(row0 + rb + (lane >> 2)) * ld + (k0 + (lane & 3) * 8);
    __builtin_amdgcn_global_load_lds((glb_uint*)gp, (lds_uint*)(lds + rb * BK), 16, 0, 0);
  }
}

// Async-stage a 128x64 fp8 tile into contiguous LDS [128][64B] (row stride 64B).
__device__ __forceinline__ void stage_f8(const uint8_t* __restrict__ g, int ld,
                                         int row0, int k0, uint8_t* lds,
                                         int wave, int lane) {
#pragma unroll
  for (int t = 0; t < 2; ++t) {
    const int rb = (t * 4 + wave) * 16;
    const uint8_t* gp = g + (size_t)(row0 + rb + (lane >> 2)) * ld + (k0 + (lane & 3) * 16);
    __builtin_amdgcn_global_load_lds((glb_uint*)gp, (lds_uint*)(lds + rb * 64), 16, 0, 0);
  }
}

// h = x @ W^T + b, bf16, double-buffered; writes h (bf16, for scores) AND
// hT (fp8 e4m3, consumed only by the MX-fp8 pv kernel).
__global__ __launch_bounds__(256) void gemm1_kernel(const bf16_t* __restrict__ xb,
                                                    const bf16_t* __restrict__ Wb,
                                                    const float* __restrict__ bias,
                                                    bf16_t* __restrict__ hout,
                                                    uint8_t* __restrict__ hT8) {
  __shared__ __align__(16) bf16_t smem[4 * TILE_B];
  const int tid = threadIdx.x;
  const int wave = tid >> 6, lane = tid & 63;
  const int wm = wave >> 1, wn = wave & 1;
  const int l15 = lane & 15, quad = lane >> 4;
  const int m0 = blockIdx.x * 128, n0 = blockIdx.y * 128;
  f32x4 acc[4][4] = {};
  const int NIT = DFEAT / BK;
  stage_async(xb, DFEAT, m0, 0, smem, wave, lane);
  stage_async(Wb, DFEAT, n0, 0, smem + TILE_B, wave, lane);
  __syncthreads();
  for (int it = 0; it < NIT; ++it) {
    bf16_t* lA = smem + (it & 1) * 2 * TILE_B;
    bf16_t* lB = lA + TILE_B;
    if (it + 1 < NIT) {
      bf16_t* nA = smem + ((it + 1) & 1) * 2 * TILE_B;
      stage_async(xb, DFEAT, m0, (it + 1) * BK, nA, wave, lane);
      stage_async(Wb, DFEAT, n0, (it + 1) * BK, nA + TILE_B, wave, lane);
    }
    bf16x8 a[4], b[4];
#pragma unroll
    for (int f = 0; f < 4; ++f) {
      a[f] = *(const bf16x8*)(lA + (wm * 64 + f * 16 + l15) * BK + quad * 8);
      b[f] = *(const bf16x8*)(lB + (wn * 64 + f * 16 + l15) * BK + quad * 8);
    }
#pragma unroll
    for (int i = 0; i < 4; ++i)
#pragma unroll
      for (int j = 0; j < 4; ++j)
        acc[i][j] = __builtin_amdgcn_mfma_f32_16x16x32_bf16(a[i], b[j], acc[i][j], 0, 0, 0);
    __syncthreads();
  }
#pragma unroll
  for (int i = 0; i < 4; ++i) {
    int rbase = m0 + wm * 64 + i * 16 + quad * 4;
#pragma unroll
    for (int j = 0; j < 4; ++j) {
      int col = n0 + wn * 64 + j * 16 + l15;
      float bv = bias[col];
      float hv[4];
#pragma unroll
      for (int r = 0; r < 4; ++r) hv[r] = acc[i][j][r] + bv;
#pragma unroll
      for (int r = 0; r < 4; ++r)
        hout[(size_t)(rbase + r) * DFEAT + col] = (bf16_t)hv[r];
      *(unsigned*)(hT8 + (size_t)col * NROWS + rbase) =
          pack_fp8x4(hv[0], hv[1], hv[2], hv[3]);  // fused transpose, fp8
    }
  }
}

// Symmetric scores (round-7 verified body; ONLY change: XCD-banded tile ids).
// Upper-triangular 128x128 tiles of P = exp(tanh(h h^T)), fp8 e4m3 out; sums
// from quantized values. Banding: tile = (id%8)*260 + id/8 -> each XCD works
// a contiguous row band, A strips L2-resident per XCD.
__global__ __launch_bounds__(256) void scores_sym_kernel(const bf16_t* __restrict__ h,
                                                         uint8_t* __restrict__ P,
                                                         float* __restrict__ lsum) {
  __shared__ __align__(16) char smem[128 * 144];  // staging 16KB / mirror 18KB overlay
  bf16_t* lA = (bf16_t*)smem;
  bf16_t* lB = (bf16_t*)(smem + 128 * BK * 2);
  uint8_t (*mir)[144] = (uint8_t(*)[144])smem;

  int t = (blockIdx.x & 7) * (NTRI / 8) + (blockIdx.x >> 3);  // XCD banding
  int bm = 0;
  while (t >= NBLK - bm) { t -= NBLK - bm; ++bm; }
  const int bn = bm + t;
  const bool offdiag = (bm != bn);
  const int m0 = bm * 128, n0 = bn * 128;

  const int tid = threadIdx.x;
  const int wave = tid >> 6, lane = tid & 63;
  const int wm = wave >> 1, wn = wave & 1;
  const int l15 = lane & 15, quad = lane >> 4;

  f32x4 acc[4][4] = {};
  for (int k0 = 0; k0 < DFEAT; k0 += BK) {
    __syncthreads();
    stage_async(h, DFEAT, m0, k0, lA, wave, lane);
    stage_async(h, DFEAT, n0, k0, lB, wave, lane);
    __syncthreads();
    bf16x8 a[4], b[4];
#pragma unroll
    for (int f = 0; f < 4; ++f) {
      a[f] = *(const bf16x8*)(lA + (wm * 64 + f * 16 + l15) * BK + quad * 8);
      b[f] = *(const bf16x8*)(lB + (wn * 64 + f * 16 + l15) * BK + quad * 8);
    }
#pragma unroll
    for (int i = 0; i < 4; ++i)
#pragma unroll
      for (int j = 0; j < 4; ++j)
        acc[i][j] = __builtin_amdgcn_mfma_f32_16x16x32_bf16(a[i], b[j], acc[i][j], 0, 0, 0);
  }
  __syncthreads();  // staging reads done; smem now free for mirror tile

  float rs[4][4];
  float cs[4];
#pragma unroll
  for (int i = 0; i < 4; ++i)
#pragma unroll
    for (int r = 0; r < 4; ++r) rs[i][r] = 0.f;
#pragma unroll
  for (int j = 0; j < 4; ++j) cs[j] = 0.f;

#pragma unroll
  for (int i = 0; i < 4; ++i) {
    const int rl_loc = wm * 64 + i * 16 + quad * 4;
    const int rbase = m0 + rl_loc;
#pragma unroll
    for (int j = 0; j < 4; ++j) {
      const int cl_loc = wn * 64 + j * 16 + l15;
      const int col = n0 + cl_loc;
      float p[4];
#pragma unroll
      for (int r = 0; r < 4; ++r) p[r] = __expf(fast_tanh(acc[i][j][r]));
      unsigned packed = pack_fp8x4(p[0], p[1], p[2], p[3]);
      // dequantize for sums so the softmax denominator matches stored P
      f32x2 d0 = __builtin_amdgcn_cvt_pk_f32_fp8(packed, false);
      f32x2 d1 = __builtin_amdgcn_cvt_pk_f32_fp8(packed, true);
      float q[4] = {d0.x, d0.y, d1.x, d1.y};
#pragma unroll
      for (int r = 0; r < 4; ++r) {
        rs[i][r] += q[r];
        cs[j] += q[r];
        P[(size_t)(rbase + r) * NROWS + col] = (uint8_t)(packed >> (8 * r));
      }
      if (offdiag) *(unsigned*)&mir[cl_loc][rl_loc] = packed;
    }
  }

#pragma unroll
  for (int off = 1; off < 16; off <<= 1)
#pragma unroll
    for (int i = 0; i < 4; ++i)
#pragma unroll
      for (int r = 0; r < 4; ++r) rs[i][r] += __shfl_xor(rs[i][r], off, 64);
  if (l15 == 0) {
#pragma unroll
    for (int i = 0; i < 4; ++i) {
      int rbase = m0 + wm * 64 + i * 16 + quad * 4;
#pragma unroll
      for (int r = 0; r < 4; ++r) atomicAdd(&lsum[rbase + r], rs[i][r]);
    }
  }

  if (offdiag) {
#pragma unroll
    for (int off = 16; off < 64; off <<= 1)
#pragma unroll
      for (int j = 0; j < 4; ++j) cs[j] += __shfl_xor(cs[j], off, 64);
    if (quad == 0) {
#pragma unroll
      for (int j = 0; j < 4; ++j)
        atomicAdd(&lsum[n0 + wn * 64 + j * 16 + l15], cs[j]);
    }
    __syncthreads();
#pragma unroll
    for (int it = 0; it < 4; ++it) {
      int q = tid + it * 256;          // 0..1023
      int c = q >> 3, r0 = (q & 7) * 16;
      uint4 v = *(const uint4*)(&mir[c][r0]);
      *(uint4*)(P + (size_t)(n0 + c) * NROWS + m0 + r0) = v;
    }
  }
}

// out = tanh((P @ h) / l): MX-fp8 (e4m3) MFMA with unity scales, K=64/iter,
// double-buffered staging. Grid (x=m=64, y=n=8) keeps same-m0 blocks on one
// XCD -> P strip L2-resident.
__global__ __launch_bounds__(256) void pv_kernel(const uint8_t* __restrict__ P,
                                                 const uint8_t* __restrict__ hT8,
                                                 const float* __restrict__ lsum,
                                                 float* __restrict__ out) {
  __shared__ __align__(16) uint8_t smem[4 * F8TILE];  // 2 phases x (A 8KB + B 8KB)
  const int tid = threadIdx.x;
  const int wave = tid >> 6, lane = tid & 63;
  const int wm = wave >> 1, wn = wave & 1;
  const int l31 = lane & 31, khalf = lane >> 5;
  const int m0 = blockIdx.x * 128, n0 = blockIdx.y * 128;
  f32x16 acc[2][2] = {};
  const int NIT = NROWS / 64;
  stage_f8(P, NROWS, m0, 0, smem, wave, lane);
  stage_f8(hT8, NROWS, n0, 0, smem + F8TILE, wave, lane);
  __syncthreads();
  for (int it = 0; it < NIT; ++it) {
    uint8_t* lA = smem + (it & 1) * 2 * F8TILE;
    uint8_t* lB = lA + F8TILE;
    if (it + 1 < NIT) {
      uint8_t* nA = smem + ((it + 1) & 1) * 2 * F8TILE;
      stage_f8(P, NROWS, m0, (it + 1) * 64, nA, wave, lane);
      stage_f8(hT8, NROWS, n0, (it + 1) * 64, nA + F8TILE, wave, lane);
    }
    i32x8 a[2], b[2];
#pragma unroll
    for (int f = 0; f < 2; ++f) {
      {
        int off = (wm * 64 + f * 32 + l31) * 64 + khalf * 32;
        i32x4 lo = *(const i32x4*)(lA + off);
        i32x4 hi = *(const i32x4*)(lA + off + 16);
        a[f] = i32x8{lo[0], lo[1], lo[2], lo[3], hi[0], hi[1], hi[2], hi[3]};
      }
      {
        int off = (wn * 64 + f * 32 + l31) * 64 + khalf * 32;
        i32x4 lo = *(const i32x4*)(lB + off);
        i32x4 hi = *(const i32x4*)(lB + off + 16);
        b[f] = i32x8{lo[0], lo[1], lo[2], lo[3], hi[0], hi[1], hi[2], hi[3]};
      }
    }
#pragma unroll
    for (int bi = 0; bi < 2; ++bi)
#pragma unroll
      for (int bj = 0; bj < 2; ++bj)
        acc[bi][bj] = __builtin_amdgcn_mfma_scale_f32_32x32x64_f8f6f4(
            a[bi], b[bj], acc[bi][bj], 0, 0, 0, 0x7F7F7F7F, 0, 0x7F7F7F7F);
    __syncthreads();
  }
  // C/D 32x32: col = lane&31, row = (reg&3) + 8*(reg>>2) + 4*(lane>>5)
#pragma unroll
  for (int bi = 0; bi < 2; ++bi)
#pragma unroll
    for (int bj = 0; bj < 2; ++bj) {
      int cbase = n0 + wn * 64 + bj * 32 + l31;
#pragma unroll
      for (int reg = 0; reg < 16; ++reg) {
        int row = m0 + wm * 64 + bi * 32 + (reg & 3) + 8 * (reg >> 2) + 4 * khalf;
        float rl = __builtin_amdgcn_rcpf(lsum[row]);
        out[(size_t)row * DFEAT + cbase] = fast_tanh(acc[bi][bj][reg] * rl);
      }
    }
}

extern "C" void kernel_launch(void* const* d_in, const int* in_sizes, int n_in,
                              void* d_out, int out_size, void* d_ws, size_t ws_size,
                              hipStream_t stream) {
  const float* x = (const float*)d_in[0];
  const float* W = (const float*)d_in[1];
  const float* bias = (const float*)d_in[2];
  float* out = (float*)d_out;

  bf16_t* xb = (bf16_t*)d_ws;                        // 16 MB
  bf16_t* Wb = xb + (size_t)NROWS * DFEAT;           // 2 MB
  bf16_t* h  = Wb + (size_t)DFEAT * DFEAT;           // 16 MB
  uint8_t* hT8 = (uint8_t*)(h + (size_t)NROWS * DFEAT);  // 8 MB (fp8)
  float* lsum = (float*)(hT8 + (size_t)DFEAT * NROWS);
  uint8_t* P = (uint8_t*)(lsum + NROWS);             // 67 MB (fp8)

  cast_kernel<<<(NROWS * DFEAT / 4) / 256, 256, 0, stream>>>(x, xb, NROWS * DFEAT / 4);
  cast_kernel<<<(DFEAT * DFEAT / 4) / 256, 256, 0, stream>>>(W, Wb, DFEAT * DFEAT / 4);
  gemm1_kernel<<<dim3(NROWS / 128, DFEAT / 128), 256, 0, stream>>>(xb, Wb, bias, h, hT8);
  hipMemsetAsync(lsum, 0, NROWS * sizeof(float), stream);
  scores_sym_kernel<<<NTRI, 256, 0, stream>>>(h, P, lsum);
  pv_kernel<<<dim3(NROWS / 128, DFEAT / 128), 256, 0, stream>>>(P, hT8, lsum, out);
}